// Round 1
// baseline (452.269 us; speedup 1.0000x reference)
//
#include <hip/hip_runtime.h>
#include <hip/hip_bf16.h>

// MHA: proj(QKV) -> flash attention -> out proj.  bf16 MFMA, fp32 accum.
#define DIN   1024
#define HEADS 16
#define DK    64
#define BATCH 4
#define SEQ   2048
#define MROWS (BATCH*SEQ)   /* 8192 */
#define HD    (HEADS*DK)    /* 1024 */

typedef unsigned short u16;
typedef unsigned int   u32;
typedef __attribute__((ext_vector_type(8))) short v8s;
typedef __attribute__((ext_vector_type(4))) float v4f;

__device__ __forceinline__ u16 f2bf(float x) {
  union { float f; u32 u; } v; v.f = x;
  u32 r = v.u + 0x7FFFu + ((v.u >> 16) & 1u);
  return (u16)(r >> 16);
}
__device__ __forceinline__ int pack2(float a, float b) {
  return (int)((u32)f2bf(a) | ((u32)f2bf(b) << 16));
}

// ---- weight transpose: W[k][n] f32 -> Wt[n][k] bf16 ----
__global__ __launch_bounds__(256) void wtrans_kernel(const float* __restrict__ in,
                                                     u16* __restrict__ out) {
  __shared__ float tile[64][65];
  int bx = blockIdx.x * 64;  // n base
  int by = blockIdx.y * 64;  // k base
  for (int i = threadIdx.x; i < 64 * 64; i += 256) {
    int r = i >> 6, c = i & 63;
    tile[r][c] = in[(size_t)(by + r) * DIN + bx + c];
  }
  __syncthreads();
  for (int i = threadIdx.x; i < 64 * 64; i += 256) {
    int r = i >> 6, c = i & 63;
    out[(size_t)(bx + r) * DIN + by + c] = f2bf(tile[c][r]);
  }
}

// ---- 128x128 tile GEMM, K=1024, N=1024.  MODE 0: A f32, out bf16 scattered
// to [B,H,S,dk].  MODE 1: A bf16, out f32 linear. ----
template <int MODE>
__global__ __launch_bounds__(256) void gemm128_kernel(const void* __restrict__ Ain,
                                                      const u16* __restrict__ Bt,
                                                      void* __restrict__ Cout) {
  __shared__ u16 A_lds[128][40];  // +8 pad, rows 80B (16B aligned)
  __shared__ u16 B_lds[128][40];
  const int tid = threadIdx.x;
  const int lane = tid & 63;
  const int wv = tid >> 6;
  const int wm = wv & 1, wn = wv >> 1;
  const int m0 = blockIdx.y * 128;
  const int n0 = blockIdx.x * 128;
  const int srow = tid >> 1;
  const int skh = (tid & 1) * 16;
  const int l15 = lane & 15;
  const int k8 = (lane >> 4) * 8;

  v4f acc[4][4];
#pragma unroll
  for (int i = 0; i < 4; i++)
#pragma unroll
    for (int j = 0; j < 4; j++) acc[i][j] = (v4f)0.f;

  for (int kk = 0; kk < DIN; kk += 32) {
    __syncthreads();
    if (MODE == 0) {
      const float* Ap = (const float*)Ain + (size_t)(m0 + srow) * DIN + kk + skh;
      float4 f0 = ((const float4*)Ap)[0];
      float4 f1 = ((const float4*)Ap)[1];
      float4 f2 = ((const float4*)Ap)[2];
      float4 f3 = ((const float4*)Ap)[3];
      int4 w0 = make_int4(pack2(f0.x, f0.y), pack2(f0.z, f0.w),
                          pack2(f1.x, f1.y), pack2(f1.z, f1.w));
      int4 w1 = make_int4(pack2(f2.x, f2.y), pack2(f2.z, f2.w),
                          pack2(f3.x, f3.y), pack2(f3.z, f3.w));
      *(int4*)&A_lds[srow][skh] = w0;
      *(int4*)&A_lds[srow][skh + 8] = w1;
    } else {
      const u16* Ap = (const u16*)Ain + (size_t)(m0 + srow) * DIN + kk + skh;
      *(int4*)&A_lds[srow][skh] = ((const int4*)Ap)[0];
      *(int4*)&A_lds[srow][skh + 8] = ((const int4*)Ap)[1];
    }
    {
      const u16* Bp = Bt + (size_t)(n0 + srow) * DIN + kk + skh;
      *(int4*)&B_lds[srow][skh] = ((const int4*)Bp)[0];
      *(int4*)&B_lds[srow][skh + 8] = ((const int4*)Bp)[1];
    }
    __syncthreads();

    v8s a[4], b[4];
#pragma unroll
    for (int mi = 0; mi < 4; mi++) a[mi] = *(const v8s*)&A_lds[wm * 64 + mi * 16 + l15][k8];
#pragma unroll
    for (int ni = 0; ni < 4; ni++) b[ni] = *(const v8s*)&B_lds[wn * 64 + ni * 16 + l15][k8];
#pragma unroll
    for (int mi = 0; mi < 4; mi++)
#pragma unroll
      for (int ni = 0; ni < 4; ni++)
        acc[mi][ni] = __builtin_amdgcn_mfma_f32_16x16x32_bf16(a[mi], b[ni], acc[mi][ni], 0, 0, 0);
  }

#pragma unroll
  for (int mi = 0; mi < 4; mi++) {
#pragma unroll
    for (int ni = 0; ni < 4; ni++) {
#pragma unroll
      for (int r = 0; r < 4; r++) {
        int row = m0 + wm * 64 + mi * 16 + ((lane >> 4) << 2) + r;
        int col = n0 + wn * 64 + ni * 16 + l15;
        float val = acc[mi][ni][r];
        if (MODE == 0) {
          int bb = row >> 11, ss = row & 2047;
          int hh = col >> 6, dd = col & 63;
          ((u16*)Cout)[((((size_t)bb * HEADS + hh) * SEQ + ss) << 6) + dd] = f2bf(val);
        } else {
          ((float*)Cout)[(size_t)row * HD + col] = val;
        }
      }
    }
  }
}

// ---- flash attention: Q,K,V bf16 [B*H][S][64] -> AO bf16 [B*S][1024] ----
__global__ __launch_bounds__(256) void attn_kernel(const u16* __restrict__ Q,
                                                   const u16* __restrict__ Kmat,
                                                   const u16* __restrict__ Vmat,
                                                   u16* __restrict__ AO) {
  __shared__ u16 K_lds[64][72];     // [key][d], +8 pad
  __shared__ u16 Vt_lds[64][72];    // [d][key], +8 pad
  __shared__ u16 P_lds[4][16][72];  // per-wave P tile [qrow][key]

  const int tid = threadIdx.x;
  const int lane = tid & 63;
  const int wv = tid >> 6;
  const int l15 = lane & 15;
  const int grp = lane >> 4;
  const int k8 = grp * 8;

  const int bh = blockIdx.y;  // 0..63
  const int qt = blockIdx.x;  // 0..31
  const size_t base = (size_t)bh * SEQ * DK;

  // Q fragments (A-operand): row=l15 of this wave's 16 rows, d = ks*32+k8..+8
  v8s qf[2];
  {
    int srow = qt * 64 + wv * 16 + l15;
    const u16* qp = Q + base + (size_t)srow * DK;
    qf[0] = *(const v8s*)(qp + k8);
    qf[1] = *(const v8s*)(qp + 32 + k8);
  }

  float mrow[4], lrow[4];
  v4f oacc[4];
#pragma unroll
  for (int r = 0; r < 4; r++) { mrow[r] = -1e30f; lrow[r] = 0.f; }
#pragma unroll
  for (int ni = 0; ni < 4; ni++) oacc[ni] = (v4f)0.f;

  const int skey = tid >> 2;
  const int sd0 = (tid & 3) * 16;

  for (int t = 0; t < SEQ / 64; ++t) {
    __syncthreads();
    {
      const u16* kp = Kmat + base + (size_t)(t * 64 + skey) * DK + sd0;
      *(int4*)&K_lds[skey][sd0] = ((const int4*)kp)[0];
      *(int4*)&K_lds[skey][sd0 + 8] = ((const int4*)kp)[1];
      const u16* vp = Vmat + base + (size_t)(t * 64 + skey) * DK + sd0;
      int4 v0 = ((const int4*)vp)[0];
      int4 v1 = ((const int4*)vp)[1];
      u16 tmp[16];
      *(int4*)&tmp[0] = v0;
      *(int4*)&tmp[8] = v1;
#pragma unroll
      for (int j = 0; j < 16; j++) Vt_lds[sd0 + j][skey] = tmp[j];
    }
    __syncthreads();

    // QK^T: S[16 x 64keys]
    v4f sacc[4];
#pragma unroll
    for (int ni = 0; ni < 4; ni++) sacc[ni] = (v4f)0.f;
#pragma unroll
    for (int ks = 0; ks < 2; ks++) {
#pragma unroll
      for (int ni = 0; ni < 4; ni++) {
        v8s bfrag = *(const v8s*)&K_lds[ni * 16 + l15][ks * 32 + k8];
        sacc[ni] = __builtin_amdgcn_mfma_f32_16x16x32_bf16(qf[ks], bfrag, sacc[ni], 0, 0, 0);
      }
    }

    // online softmax (scale 1/sqrt(64) = 0.125), rows = grp*4+r
    float pvv[4][4];
    float fac[4];
#pragma unroll
    for (int r = 0; r < 4; r++) {
      float mx = -1e30f;
#pragma unroll
      for (int ni = 0; ni < 4; ni++) {
        float s = sacc[ni][r] * 0.125f;
        pvv[ni][r] = s;
        mx = fmaxf(mx, s);
      }
#pragma unroll
      for (int off = 1; off < 16; off <<= 1) mx = fmaxf(mx, __shfl_xor(mx, off));
      float mnew = fmaxf(mrow[r], mx);
      fac[r] = __expf(mrow[r] - mnew);
      float ls = 0.f;
#pragma unroll
      for (int ni = 0; ni < 4; ni++) {
        float p = __expf(pvv[ni][r] - mnew);
        pvv[ni][r] = p;
        ls += p;
      }
#pragma unroll
      for (int off = 1; off < 16; off <<= 1) ls += __shfl_xor(ls, off);
      mrow[r] = mnew;
      lrow[r] = lrow[r] * fac[r] + ls;
    }
#pragma unroll
    for (int ni = 0; ni < 4; ni++)
#pragma unroll
      for (int r = 0; r < 4; r++) oacc[ni][r] *= fac[r];

    // P -> LDS (bf16), same-wave producer/consumer
#pragma unroll
    for (int ni = 0; ni < 4; ni++)
#pragma unroll
      for (int r = 0; r < 4; r++)
        P_lds[wv][grp * 4 + r][ni * 16 + l15] = f2bf(pvv[ni][r]);
    asm volatile("s_waitcnt lgkmcnt(0)" ::: "memory");

    // PV: out += P[16 x 64] @ V[64 x 64]
#pragma unroll
    for (int ks = 0; ks < 2; ks++) {
      v8s pa = *(const v8s*)&P_lds[wv][l15][ks * 32 + k8];
#pragma unroll
      for (int ni = 0; ni < 4; ni++) {
        v8s bfrag = *(const v8s*)&Vt_lds[ni * 16 + l15][ks * 32 + k8];
        oacc[ni] = __builtin_amdgcn_mfma_f32_16x16x32_bf16(pa, bfrag, oacc[ni], 0, 0, 0);
      }
    }
  }

  // epilogue: AO[b*S+s][h*64+d] = oacc / l
  const int bb = bh >> 4, hh = bh & 15;
#pragma unroll
  for (int ni = 0; ni < 4; ni++) {
#pragma unroll
    for (int r = 0; r < 4; r++) {
      int srow2 = qt * 64 + wv * 16 + grp * 4 + r;
      int col = hh * DK + ni * 16 + l15;
      AO[((size_t)bb * SEQ + srow2) * HD + col] = f2bf(oacc[ni][r] / lrow[r]);
    }
  }
}

extern "C" void kernel_launch(void* const* d_in, const int* in_sizes, int n_in,
                              void* d_out, int out_size, void* d_ws, size_t ws_size,
                              hipStream_t stream) {
  const float* q_in = (const float*)d_in[0];
  const float* k_in = (const float*)d_in[1];
  const float* v_in = (const float*)d_in[2];
  const float* Wq = (const float*)d_in[3];
  const float* Wk = (const float*)d_in[4];
  const float* Wv = (const float*)d_in[5];
  const float* Wo = (const float*)d_in[6];
  float* out = (float*)d_out;

  u16* ws = (u16*)d_ws;
  u16* Wtq = ws;                       // [1024][1024] bf16 each
  u16* Wtk = Wtq + (1u << 20);
  u16* Wtv = Wtk + (1u << 20);
  u16* Wto = Wtv + (1u << 20);
  u16* Qb = Wto + (1u << 20);          // [B*H][S][64] bf16
  u16* Kb = Qb + (size_t)MROWS * HD;
  u16* Vb = Kb + (size_t)MROWS * HD;
  u16* AO = Vb + (size_t)MROWS * HD;   // [B*S][1024] bf16

  dim3 tb(256);
  dim3 tg(16, 16);
  wtrans_kernel<<<tg, tb, 0, stream>>>(Wq, Wtq);
  wtrans_kernel<<<tg, tb, 0, stream>>>(Wk, Wtk);
  wtrans_kernel<<<tg, tb, 0, stream>>>(Wv, Wtv);
  wtrans_kernel<<<tg, tb, 0, stream>>>(Wo, Wto);

  dim3 gg(HD / 128, MROWS / 128);
  gemm128_kernel<0><<<gg, tb, 0, stream>>>(q_in, Wtq, Qb);
  gemm128_kernel<0><<<gg, tb, 0, stream>>>(k_in, Wtk, Kb);
  gemm128_kernel<0><<<gg, tb, 0, stream>>>(v_in, Wtv, Vb);

  dim3 ag(SEQ / 64, BATCH * HEADS);
  attn_kernel<<<ag, tb, 0, stream>>>(Qb, Kb, Vb, AO);

  gemm128_kernel<1><<<gg, tb, 0, stream>>>(AO, Wto, out);
}

// Round 2
// 370.477 us; speedup vs baseline: 1.2208x; 1.2208x over previous
//
#include <hip/hip_runtime.h>
#include <hip/hip_bf16.h>

// MHA: proj(QKV) -> flash attention (swapped-QK^T, in-register softmax) -> out proj.
#define DIN   1024
#define HEADS 16
#define DK    64
#define BATCH 4
#define SEQ   2048
#define MROWS (BATCH*SEQ)   /* 8192 */
#define HD    (HEADS*DK)    /* 1024 */

typedef unsigned short u16;
typedef unsigned int   u32;
typedef __attribute__((ext_vector_type(8))) short v8s;
typedef __attribute__((ext_vector_type(4))) float v4f;

__device__ __forceinline__ u16 f2bf(float x) {
  union { float f; u32 u; } v; v.f = x;
  u32 r = v.u + 0x7FFFu + ((v.u >> 16) & 1u);
  return (u16)(r >> 16);
}
__device__ __forceinline__ int pack2(float a, float b) {
  return (int)((u32)f2bf(a) | ((u32)f2bf(b) << 16));
}

// ---- weight transpose: W[k][n] f32 -> Wt[n][k] bf16 ----
__global__ __launch_bounds__(256) void wtrans_kernel(const float* __restrict__ in,
                                                     u16* __restrict__ out) {
  __shared__ float tile[64][65];
  int bx = blockIdx.x * 64;  // n base
  int by = blockIdx.y * 64;  // k base
  for (int i = threadIdx.x; i < 64 * 64; i += 256) {
    int r = i >> 6, c = i & 63;
    tile[r][c] = in[(size_t)(by + r) * DIN + bx + c];
  }
  __syncthreads();
  for (int i = threadIdx.x; i < 64 * 64; i += 256) {
    int r = i >> 6, c = i & 63;
    out[(size_t)(bx + r) * DIN + by + c] = f2bf(tile[c][r]);
  }
}

// ---- V transpose: Vb[bh][s][d] bf16 -> Vt[bh][d][s] bf16 ----
__global__ __launch_bounds__(256) void vtrans_kernel(const u16* __restrict__ in,
                                                     u16* __restrict__ out) {
  __shared__ u16 t[64][72];
  const int s0 = blockIdx.x * 64;
  const int bh = blockIdx.y;
  const int r = threadIdx.x >> 2;
  const int c = (threadIdx.x & 3) * 16;
  const u16* ip = in + (size_t)bh * SEQ * DK + (size_t)(s0 + r) * DK + c;
  *(int4*)&t[r][c] = ((const int4*)ip)[0];
  *(int4*)&t[r][c + 8] = ((const int4*)ip)[1];
  __syncthreads();
  u16 tmp[16];
#pragma unroll
  for (int j = 0; j < 16; j++) tmp[j] = t[c + j][r];
  u16* op = out + (size_t)bh * DK * SEQ + (size_t)r * SEQ + s0 + c;
  ((int4*)op)[0] = *(int4*)&tmp[0];
  ((int4*)op)[1] = *(int4*)&tmp[8];
}

// ---- 128x128 tile GEMM, K=1024, N=1024.  MODE 0: A f32, out bf16 scattered
// to [B,H,S,dk].  MODE 1: A bf16, out f32 linear.  1D grid, XCD swizzle. ----
template <int MODE>
__global__ __launch_bounds__(256) void gemm128_kernel(const void* __restrict__ Ain,
                                                      const u16* __restrict__ Bt,
                                                      void* __restrict__ Cout) {
  __shared__ u16 A_lds[128][40];  // +8 pad, rows 80B (16B aligned)
  __shared__ u16 B_lds[128][40];
  const int tid = threadIdx.x;
  const int lane = tid & 63;
  const int wv = tid >> 6;
  const int wm = wv & 1, wn = wv >> 1;
  // 512 blocks; XCD-bijective swizzle (512 % 8 == 0): XCD k gets 8 row-panels
  const int bid = blockIdx.x;
  const int swz = (bid & 7) * 64 + (bid >> 3);
  const int m0 = (swz >> 3) * 128;
  const int n0 = (swz & 7) * 128;
  const int srow = tid >> 1;
  const int skh = (tid & 1) * 16;
  const int l15 = lane & 15;
  const int k8 = (lane >> 4) * 8;

  v4f acc[4][4];
#pragma unroll
  for (int i = 0; i < 4; i++)
#pragma unroll
    for (int j = 0; j < 4; j++) acc[i][j] = (v4f)0.f;

  for (int kk = 0; kk < DIN; kk += 32) {
    __syncthreads();
    if (MODE == 0) {
      const float* Ap = (const float*)Ain + (size_t)(m0 + srow) * DIN + kk + skh;
      float4 f0 = ((const float4*)Ap)[0];
      float4 f1 = ((const float4*)Ap)[1];
      float4 f2 = ((const float4*)Ap)[2];
      float4 f3 = ((const float4*)Ap)[3];
      int4 w0 = make_int4(pack2(f0.x, f0.y), pack2(f0.z, f0.w),
                          pack2(f1.x, f1.y), pack2(f1.z, f1.w));
      int4 w1 = make_int4(pack2(f2.x, f2.y), pack2(f2.z, f2.w),
                          pack2(f3.x, f3.y), pack2(f3.z, f3.w));
      *(int4*)&A_lds[srow][skh] = w0;
      *(int4*)&A_lds[srow][skh + 8] = w1;
    } else {
      const u16* Ap = (const u16*)Ain + (size_t)(m0 + srow) * DIN + kk + skh;
      *(int4*)&A_lds[srow][skh] = ((const int4*)Ap)[0];
      *(int4*)&A_lds[srow][skh + 8] = ((const int4*)Ap)[1];
    }
    {
      const u16* Bp = Bt + (size_t)(n0 + srow) * DIN + kk + skh;
      *(int4*)&B_lds[srow][skh] = ((const int4*)Bp)[0];
      *(int4*)&B_lds[srow][skh + 8] = ((const int4*)Bp)[1];
    }
    __syncthreads();

    v8s a[4], b[4];
#pragma unroll
    for (int mi = 0; mi < 4; mi++) a[mi] = *(const v8s*)&A_lds[wm * 64 + mi * 16 + l15][k8];
#pragma unroll
    for (int ni = 0; ni < 4; ni++) b[ni] = *(const v8s*)&B_lds[wn * 64 + ni * 16 + l15][k8];
#pragma unroll
    for (int mi = 0; mi < 4; mi++)
#pragma unroll
      for (int ni = 0; ni < 4; ni++)
        acc[mi][ni] = __builtin_amdgcn_mfma_f32_16x16x32_bf16(a[mi], b[ni], acc[mi][ni], 0, 0, 0);
  }

#pragma unroll
  for (int mi = 0; mi < 4; mi++) {
#pragma unroll
    for (int ni = 0; ni < 4; ni++) {
#pragma unroll
      for (int r = 0; r < 4; r++) {
        int row = m0 + wm * 64 + mi * 16 + ((lane >> 4) << 2) + r;
        int col = n0 + wn * 64 + ni * 16 + l15;
        float val = acc[mi][ni][r];
        if (MODE == 0) {
          int bb = row >> 11, ss = row & 2047;
          int hh = col >> 6, dd = col & 63;
          ((u16*)Cout)[((((size_t)bb * HEADS + hh) * SEQ + ss) << 6) + dd] = f2bf(val);
        } else {
          ((float*)Cout)[(size_t)row * HD + col] = val;
        }
      }
    }
  }
}

// ---- flash attention (swapped QK^T): Q,K bf16 [B*H][S][64], Vt bf16 [B*H][64][S]
//      -> AO bf16 [B*S][1024].  Each lane owns one q row's P slice. ----
__global__ __launch_bounds__(256) void attn_kernel(const u16* __restrict__ Q,
                                                   const u16* __restrict__ Kmat,
                                                   const u16* __restrict__ Vt,
                                                   u16* __restrict__ AO) {
  __shared__ u16 K_lds[64][72];     // [key][d], 144B rows
  __shared__ u16 Vt_lds[64][72];    // [d][key]
  __shared__ u16 P_lds[4][16][72];  // per-wave P^T stash: [q(l15)][key]

  const int tid = threadIdx.x;
  const int lane = tid & 63;
  const int wv = tid >> 6;
  const int l15 = lane & 15;
  const int grp = lane >> 4;
  const int k8 = grp * 8;

  // XCD-bijective swizzle (2048 % 8 == 0): XCD k gets bh in [8k, 8k+8) ->
  // that XCD's K/V working set = 8 * 512KB = 4MB = its L2.
  const int bid = blockIdx.x;
  const int swz = (bid & 7) * 256 + (bid >> 3);
  const int bh = swz >> 5;
  const int qt = swz & 31;
  const size_t base = (size_t)bh * SEQ * DK;

  // Q as B-fragment, pre-scaled by 1/sqrt(64)=0.125 (exact exponent shift)
  v8s qf[2];
  {
    const int q = qt * 64 + wv * 16 + l15;
    const u16* qp = Q + base + (size_t)q * DK;
    qf[0] = *(const v8s*)(qp + k8);
    qf[1] = *(const v8s*)(qp + 32 + k8);
#pragma unroll
    for (int j = 0; j < 8; j++) {
      union { float f; u32 u; } a;
      a.u = ((u32)(u16)qf[0][j]) << 16; a.f *= 0.125f; qf[0][j] = (short)(a.u >> 16);
      a.u = ((u32)(u16)qf[1][j]) << 16; a.f *= 0.125f; qf[1][j] = (short)(a.u >> 16);
    }
  }

  float mrow = -1e30f, lrow = 0.f;
  v4f oacc[4];
#pragma unroll
  for (int db = 0; db < 4; db++) oacc[db] = (v4f)0.f;

  const int srow = tid >> 2;        // 0..63
  const int sc16 = (tid & 3) * 16;  // 0,16,32,48

  for (int t = 0; t < SEQ / 64; ++t) {
    __syncthreads();
    {
      const u16* kp = Kmat + base + (size_t)(t * 64 + srow) * DK + sc16;
      *(int4*)&K_lds[srow][sc16] = ((const int4*)kp)[0];
      *(int4*)&K_lds[srow][sc16 + 8] = ((const int4*)kp)[1];
      const u16* vp = Vt + base + (size_t)srow * SEQ + t * 64 + sc16;
      *(int4*)&Vt_lds[srow][sc16] = ((const int4*)vp)[0];
      *(int4*)&Vt_lds[srow][sc16 + 8] = ((const int4*)vp)[1];
    }
    __syncthreads();

    // S^T[key][q] = K · Q^T : lane (q=l15, grp) gets keys kb*16 + grp*4 + r
    v4f sacc[4];
#pragma unroll
    for (int kb = 0; kb < 4; kb++) sacc[kb] = (v4f)0.f;
#pragma unroll
    for (int ks = 0; ks < 2; ks++) {
#pragma unroll
      for (int kb = 0; kb < 4; kb++) {
        v8s kf = *(const v8s*)&K_lds[kb * 16 + l15][ks * 32 + k8];
        sacc[kb] = __builtin_amdgcn_mfma_f32_16x16x32_bf16(kf, qf[ks], sacc[kb], 0, 0, 0);
      }
    }

    // online softmax: row q = l15, spread over 4 grp-lanes x 16 regs
    float mx = -1e30f;
#pragma unroll
    for (int kb = 0; kb < 4; kb++)
#pragma unroll
      for (int r = 0; r < 4; r++) mx = fmaxf(mx, sacc[kb][r]);
    mx = fmaxf(mx, __shfl_xor(mx, 16));
    mx = fmaxf(mx, __shfl_xor(mx, 32));
    const float mnew = fmaxf(mrow, mx);
    const float fac = __expf(mrow - mnew);
    float p[4][4];
    float ls = 0.f;
#pragma unroll
    for (int kb = 0; kb < 4; kb++)
#pragma unroll
      for (int r = 0; r < 4; r++) {
        float e = __expf(sacc[kb][r] - mnew);
        p[kb][r] = e;
        ls += e;
      }
    ls += __shfl_xor(ls, 16);
    ls += __shfl_xor(ls, 32);
    mrow = mnew;
    lrow = lrow * fac + ls;
#pragma unroll
    for (int db = 0; db < 4; db++) oacc[db] *= fac;

    // P^T -> per-wave LDS: keys kb*16+grp*4..+3 are reg-adjacent -> b64 writes
#pragma unroll
    for (int kb = 0; kb < 4; kb++) {
      int2 w;
      w.x = pack2(p[kb][0], p[kb][1]);
      w.y = pack2(p[kb][2], p[kb][3]);
      *(int2*)&P_lds[wv][l15][kb * 16 + grp * 4] = w;
    }
    asm volatile("s_waitcnt lgkmcnt(0)" ::: "memory");

    // O^T += V^T · P^T : lane (q=l15, grp) accumulates d = db*16 + grp*4 + r
#pragma unroll
    for (int ks = 0; ks < 2; ks++) {
      v8s pf = *(const v8s*)&P_lds[wv][l15][ks * 32 + k8];
#pragma unroll
      for (int db = 0; db < 4; db++) {
        v8s vf = *(const v8s*)&Vt_lds[db * 16 + l15][ks * 32 + k8];
        oacc[db] = __builtin_amdgcn_mfma_f32_16x16x32_bf16(vf, pf, oacc[db], 0, 0, 0);
      }
    }
  }

  // epilogue: AO[b*S+q][h*64+d], d-quad per reg block -> 8B packed stores
  const int bb = bh >> 4, hh = bh & 15;
  const int q = qt * 64 + wv * 16 + l15;
  const float inv = 1.0f / lrow;
  const size_t rowbase = ((size_t)bb * SEQ + q) * HD + hh * DK;
#pragma unroll
  for (int db = 0; db < 4; db++) {
    int2 w;
    w.x = pack2(oacc[db][0] * inv, oacc[db][1] * inv);
    w.y = pack2(oacc[db][2] * inv, oacc[db][3] * inv);
    *(int2*)&AO[rowbase + db * 16 + grp * 4] = w;
  }
}

extern "C" void kernel_launch(void* const* d_in, const int* in_sizes, int n_in,
                              void* d_out, int out_size, void* d_ws, size_t ws_size,
                              hipStream_t stream) {
  const float* q_in = (const float*)d_in[0];
  const float* k_in = (const float*)d_in[1];
  const float* v_in = (const float*)d_in[2];
  const float* Wq = (const float*)d_in[3];
  const float* Wk = (const float*)d_in[4];
  const float* Wv = (const float*)d_in[5];
  const float* Wo = (const float*)d_in[6];
  float* out = (float*)d_out;

  u16* ws = (u16*)d_ws;
  u16* Wtq = ws;                       // 4 x [1024][1024] bf16
  u16* Wtk = Wtq + (1u << 20);
  u16* Wtv = Wtk + (1u << 20);
  u16* Wto = Wtv + (1u << 20);
  u16* Qb = Wto + (1u << 20);          // [B*H][S][64] bf16
  u16* Kb = Qb + (size_t)MROWS * HD;
  u16* Vb = Kb + (size_t)MROWS * HD;
  u16* AO = Vb + (size_t)MROWS * HD;   // [B*S][1024] bf16
  u16* Vt = AO + (size_t)MROWS * HD;   // [B*H][64][S] bf16

  dim3 tb(256);
  dim3 tg(16, 16);
  wtrans_kernel<<<tg, tb, 0, stream>>>(Wq, Wtq);
  wtrans_kernel<<<tg, tb, 0, stream>>>(Wk, Wtk);
  wtrans_kernel<<<tg, tb, 0, stream>>>(Wv, Wtv);
  wtrans_kernel<<<tg, tb, 0, stream>>>(Wo, Wtv + (1u << 20));

  gemm128_kernel<0><<<dim3(512), tb, 0, stream>>>(q_in, Wtq, Qb);
  gemm128_kernel<0><<<dim3(512), tb, 0, stream>>>(k_in, Wtk, Kb);
  gemm128_kernel<0><<<dim3(512), tb, 0, stream>>>(v_in, Wtv, Vb);

  vtrans_kernel<<<dim3(SEQ / 64, BATCH * HEADS), tb, 0, stream>>>(Vb, Vt);

  attn_kernel<<<dim3(2048), tb, 0, stream>>>(Qb, Kb, Vt, AO);

  gemm128_kernel<1><<<dim3(512), tb, 0, stream>>>(AO, Wto, out);
}

// Round 3
// 301.211 us; speedup vs baseline: 1.5015x; 1.2300x over previous
//
#include <hip/hip_runtime.h>
#include <hip/hip_bf16.h>

// MHA: cvt->proj(QKV via DMA-staged MFMA GEMM) -> flash attention -> out proj.
#define DIN   1024
#define HEADS 16
#define DK    64
#define BATCH 4
#define SEQ   2048
#define MROWS (BATCH*SEQ)   /* 8192 */
#define HD    (HEADS*DK)    /* 1024 */

typedef unsigned short u16;
typedef unsigned int   u32;
typedef __attribute__((ext_vector_type(8))) short v8s;
typedef __attribute__((ext_vector_type(4))) float v4f;

__device__ __forceinline__ u16 f2bf(float x) {
  union { float f; u32 u; } v; v.f = x;
  u32 r = v.u + 0x7FFFu + ((v.u >> 16) & 1u);
  return (u16)(r >> 16);
}
// v_cvt_pk_bf16_f32: lo->bits[15:0], hi->bits[31:16], RNE
__device__ __forceinline__ int cvtpk(float lo, float hi) {
  int r;
  asm("v_cvt_pk_bf16_f32 %0, %1, %2" : "=v"(r) : "v"(lo), "v"(hi));
  return r;
}
// async global->LDS DMA, 16B per lane, lds base must be wave-uniform
__device__ __forceinline__ void gload16(const void* g, void* l) {
  __builtin_amdgcn_global_load_lds(
      (__attribute__((address_space(1))) void*)(uintptr_t)(g),
      (__attribute__((address_space(3))) void*)(uintptr_t)(l), 16, 0, 0);
}

// ---- weight transpose: W[k][n] f32 -> Wt[n][k] bf16 ----
__global__ __launch_bounds__(256) void wtrans_kernel(const float* __restrict__ in,
                                                     u16* __restrict__ out) {
  __shared__ float tile[64][65];
  int bx = blockIdx.x * 64;  // n base
  int by = blockIdx.y * 64;  // k base
  for (int i = threadIdx.x; i < 64 * 64; i += 256) {
    int r = i >> 6, c = i & 63;
    tile[r][c] = in[(size_t)(by + r) * DIN + bx + c];
  }
  __syncthreads();
  for (int i = threadIdx.x; i < 64 * 64; i += 256) {
    int r = i >> 6, c = i & 63;
    out[(size_t)(bx + r) * DIN + by + c] = f2bf(tile[c][r]);
  }
}

// ---- f32 -> bf16 convert (8 elems/thread) ----
__global__ __launch_bounds__(256) void cvt_kernel(const float* __restrict__ in,
                                                  u16* __restrict__ out) {
  int i = blockIdx.x * 256 + threadIdx.x;  // grid sized exactly
  const float4* p = (const float4*)(in + (size_t)i * 8);
  float4 a = p[0], b = p[1];
  int4 w;
  w.x = cvtpk(a.x, a.y);
  w.y = cvtpk(a.z, a.w);
  w.z = cvtpk(b.x, b.y);
  w.w = cvtpk(b.z, b.w);
  *(int4*)(out + (size_t)i * 8) = w;
}

// ---- V transpose: Vb[bh][s][d] bf16 -> Vt[bh][d][s] bf16 ----
__global__ __launch_bounds__(256) void vtrans_kernel(const u16* __restrict__ in,
                                                     u16* __restrict__ out) {
  __shared__ u16 t[64][72];
  const int s0 = blockIdx.x * 64;
  const int bh = blockIdx.y;
  const int r = threadIdx.x >> 2;
  const int c = (threadIdx.x & 3) * 16;
  const u16* ip = in + (size_t)bh * SEQ * DK + (size_t)(s0 + r) * DK + c;
  *(int4*)&t[r][c] = ((const int4*)ip)[0];
  *(int4*)&t[r][c + 8] = ((const int4*)ip)[1];
  __syncthreads();
  u16 tmp[16];
#pragma unroll
  for (int j = 0; j < 16; j++) tmp[j] = t[c + j][r];
  u16* op = out + (size_t)bh * DK * SEQ + (size_t)r * SEQ + s0 + c;
  ((int4*)op)[0] = *(int4*)&tmp[0];
  ((int4*)op)[1] = *(int4*)&tmp[8];
}

// ---- 128x128 tile GEMM, K=1024, all-bf16 operands, global_load_lds staging.
// MODE 0: out bf16 scattered to [B,H,S,dk].  MODE 1: out f32 linear. ----
template <int MODE>
__global__ __launch_bounds__(256) void gemm128_kernel(const u16* __restrict__ A,
                                                      const u16* __restrict__ Bt,
                                                      void* __restrict__ Cout) {
  __shared__ u16 A_lds[128][32];  // linear (gload_lds requires it)
  __shared__ u16 B_lds[128][32];
  const int tid = threadIdx.x;
  const int lane = tid & 63;
  const int wv = tid >> 6;
  const int wm = wv & 1, wn = wv >> 1;
  const int bid = blockIdx.x;
  const int swz = (bid & 7) * 64 + (bid >> 3);  // 512 % 8 == 0, bijective
  const int m0 = (swz >> 3) * 128;
  const int n0 = (swz & 7) * 128;
  const int l15 = lane & 15;
  const int k8 = (lane >> 4) * 8;

  // staging: chunk = 1KB = 16 rows of [x][32]; wave wv owns chunks {wv, wv+4}
  const int srow = wv * 16 + (lane >> 2);
  const int scol = (lane & 3) * 8;
  const u16* ga = A + (size_t)(m0 + srow) * DIN + scol;
  const u16* gb = Bt + (size_t)(n0 + srow) * DIN + scol;
  u16* la0 = &A_lds[wv * 16][0];
  u16* la1 = &A_lds[wv * 16 + 64][0];
  u16* lb0 = &B_lds[wv * 16][0];
  u16* lb1 = &B_lds[wv * 16 + 64][0];

  v4f acc[4][4];
#pragma unroll
  for (int i = 0; i < 4; i++)
#pragma unroll
    for (int j = 0; j < 4; j++) acc[i][j] = (v4f)0.f;

  for (int kk = 0; kk < DIN; kk += 32) {
    __syncthreads();
    gload16(ga + kk, la0);
    gload16(ga + (size_t)64 * DIN + kk, la1);
    gload16(gb + kk, lb0);
    gload16(gb + (size_t)64 * DIN + kk, lb1);
    __syncthreads();

    v8s a[4], b[4];
#pragma unroll
    for (int mi = 0; mi < 4; mi++) a[mi] = *(const v8s*)&A_lds[wm * 64 + mi * 16 + l15][k8];
#pragma unroll
    for (int ni = 0; ni < 4; ni++) b[ni] = *(const v8s*)&B_lds[wn * 64 + ni * 16 + l15][k8];
#pragma unroll
    for (int mi = 0; mi < 4; mi++)
#pragma unroll
      for (int ni = 0; ni < 4; ni++)
        acc[mi][ni] = __builtin_amdgcn_mfma_f32_16x16x32_bf16(a[mi], b[ni], acc[mi][ni], 0, 0, 0);
  }

  const int grp = lane >> 4;
#pragma unroll
  for (int mi = 0; mi < 4; mi++) {
#pragma unroll
    for (int ni = 0; ni < 4; ni++) {
      if (MODE == 0) {
        int w01 = cvtpk(acc[mi][ni][0], acc[mi][ni][1]);
        int w23 = cvtpk(acc[mi][ni][2], acc[mi][ni][3]);
        u16 h[4] = {(u16)w01, (u16)(w01 >> 16), (u16)w23, (u16)(w23 >> 16)};
#pragma unroll
        for (int r = 0; r < 4; r++) {
          int row = m0 + wm * 64 + mi * 16 + grp * 4 + r;
          int col = n0 + wn * 64 + ni * 16 + l15;
          int bb = row >> 11, ss = row & 2047;
          int hh = col >> 6, dd = col & 63;
          ((u16*)Cout)[((((size_t)bb * HEADS + hh) * SEQ + ss) << 6) + dd] = h[r];
        }
      } else {
#pragma unroll
        for (int r = 0; r < 4; r++) {
          int row = m0 + wm * 64 + mi * 16 + grp * 4 + r;
          int col = n0 + wn * 64 + ni * 16 + l15;
          ((float*)Cout)[(size_t)row * HD + col] = acc[mi][ni][r];
        }
      }
    }
  }
}

// ---- flash attention (swapped QK^T, log2 domain, defer-max) ----
__global__ __launch_bounds__(256) void attn_kernel(const u16* __restrict__ Q,
                                                   const u16* __restrict__ Kmat,
                                                   const u16* __restrict__ Vt,
                                                   u16* __restrict__ AO) {
  __shared__ u16 K_lds[64][72];
  __shared__ u16 Vt_lds[64][72];
  __shared__ u16 P_lds[4][16][72];

  const int tid = threadIdx.x;
  const int lane = tid & 63;
  const int wv = tid >> 6;
  const int l15 = lane & 15;
  const int grp = lane >> 4;
  const int k8 = grp * 8;

  const int bid = blockIdx.x;
  const int swz = (bid & 7) * 256 + (bid >> 3);  // XCD: 8 bh per XCD -> K/V L2-fit
  const int bh = swz >> 5;
  const int qt = swz & 31;
  const size_t base = (size_t)bh * SEQ * DK;

  // Q pre-scaled by (1/sqrt(64)) * log2(e) -> scores in log2 domain
  v8s qf[2];
  {
    const int q = qt * 64 + wv * 16 + l15;
    const u16* qp = Q + base + (size_t)q * DK;
    qf[0] = *(const v8s*)(qp + k8);
    qf[1] = *(const v8s*)(qp + 32 + k8);
    const float SCL = 0.125f * 1.44269504f;
#pragma unroll
    for (int j = 0; j < 8; j++) {
      union { float f; u32 u; } a;
      a.u = ((u32)(u16)qf[0][j]) << 16; a.f *= SCL; qf[0][j] = (short)f2bf(a.f);
      a.u = ((u32)(u16)qf[1][j]) << 16; a.f *= SCL; qf[1][j] = (short)f2bf(a.f);
    }
  }

  float mrow = -1e30f, lrow = 0.f;
  v4f oacc[4];
#pragma unroll
  for (int db = 0; db < 4; db++) oacc[db] = (v4f)0.f;

  const int srow = tid >> 2;
  const int sc16 = (tid & 3) * 16;

  for (int t = 0; t < SEQ / 64; ++t) {
    __syncthreads();
    {
      const u16* kp = Kmat + base + (size_t)(t * 64 + srow) * DK + sc16;
      *(int4*)&K_lds[srow][sc16] = ((const int4*)kp)[0];
      *(int4*)&K_lds[srow][sc16 + 8] = ((const int4*)kp)[1];
      const u16* vp = Vt + base + (size_t)srow * SEQ + t * 64 + sc16;
      *(int4*)&Vt_lds[srow][sc16] = ((const int4*)vp)[0];
      *(int4*)&Vt_lds[srow][sc16 + 8] = ((const int4*)vp)[1];
    }
    __syncthreads();

    // S^T[key][q] = K · Q^T
    v4f sacc[4];
#pragma unroll
    for (int kb = 0; kb < 4; kb++) sacc[kb] = (v4f)0.f;
    __builtin_amdgcn_s_setprio(1);
#pragma unroll
    for (int ks = 0; ks < 2; ks++) {
#pragma unroll
      for (int kb = 0; kb < 4; kb++) {
        v8s kf = *(const v8s*)&K_lds[kb * 16 + l15][ks * 32 + k8];
        sacc[kb] = __builtin_amdgcn_mfma_f32_16x16x32_bf16(kf, qf[ks], sacc[kb], 0, 0, 0);
      }
    }
    __builtin_amdgcn_s_setprio(0);

    // online softmax in log2 domain; defer-max (THR=8 -> P <= 256)
    float mx = -1e30f;
#pragma unroll
    for (int kb = 0; kb < 4; kb++)
#pragma unroll
      for (int r = 0; r < 4; r++) mx = fmaxf(mx, sacc[kb][r]);
    mx = fmaxf(mx, __shfl_xor(mx, 16));
    mx = fmaxf(mx, __shfl_xor(mx, 32));
    if (__any(mx - mrow > 8.f)) {
      float mnew = fmaxf(mrow, mx);
      float fac = __builtin_amdgcn_exp2f(mrow - mnew);
      lrow *= fac;
#pragma unroll
      for (int db = 0; db < 4; db++) oacc[db] *= fac;
      mrow = mnew;
    }
    float p[4][4];
    float ls = 0.f;
#pragma unroll
    for (int kb = 0; kb < 4; kb++)
#pragma unroll
      for (int r = 0; r < 4; r++) {
        float e = __builtin_amdgcn_exp2f(sacc[kb][r] - mrow);
        p[kb][r] = e;
        ls += e;
      }
    ls += __shfl_xor(ls, 16);
    ls += __shfl_xor(ls, 32);
    lrow += ls;

    // P^T -> per-wave LDS (b64 writes, cvt_pk packed)
#pragma unroll
    for (int kb = 0; kb < 4; kb++) {
      int2 w;
      w.x = cvtpk(p[kb][0], p[kb][1]);
      w.y = cvtpk(p[kb][2], p[kb][3]);
      *(int2*)&P_lds[wv][l15][kb * 16 + grp * 4] = w;
    }
    asm volatile("s_waitcnt lgkmcnt(0)" ::: "memory");

    // O^T += V^T · P^T
    __builtin_amdgcn_s_setprio(1);
#pragma unroll
    for (int ks = 0; ks < 2; ks++) {
      v8s pf = *(const v8s*)&P_lds[wv][l15][ks * 32 + k8];
#pragma unroll
      for (int db = 0; db < 4; db++) {
        v8s vf = *(const v8s*)&Vt_lds[db * 16 + l15][ks * 32 + k8];
        oacc[db] = __builtin_amdgcn_mfma_f32_16x16x32_bf16(vf, pf, oacc[db], 0, 0, 0);
      }
    }
    __builtin_amdgcn_s_setprio(0);
  }

  const int bb = bh >> 4, hh = bh & 15;
  const int q = qt * 64 + wv * 16 + l15;
  const float inv = 1.0f / lrow;
  const size_t rowbase = ((size_t)bb * SEQ + q) * HD + hh * DK;
#pragma unroll
  for (int db = 0; db < 4; db++) {
    int2 w;
    w.x = cvtpk(oacc[db][0] * inv, oacc[db][1] * inv);
    w.y = cvtpk(oacc[db][2] * inv, oacc[db][3] * inv);
    *(int2*)&AO[rowbase + db * 16 + grp * 4] = w;
  }
}

extern "C" void kernel_launch(void* const* d_in, const int* in_sizes, int n_in,
                              void* d_out, int out_size, void* d_ws, size_t ws_size,
                              hipStream_t stream) {
  const float* q_in = (const float*)d_in[0];
  const float* k_in = (const float*)d_in[1];
  const float* v_in = (const float*)d_in[2];
  const float* Wq = (const float*)d_in[3];
  const float* Wk = (const float*)d_in[4];
  const float* Wv = (const float*)d_in[5];
  const float* Wo = (const float*)d_in[6];
  float* out = (float*)d_out;

  u16* ws = (u16*)d_ws;
  const size_t M1 = (size_t)1 << 20;
  u16* Wtq = ws;             // 4 x [1024][1024] bf16 (8MB)
  u16* Wtk = Wtq + M1;
  u16* Wtv = Wtk + M1;
  u16* Wto = Wtv + M1;
  u16* X  = Wto + M1;                  // 16MB scratch: bf16 activations / Vt
  u16* Qb = X + (size_t)MROWS * DIN;   // [B*H][S][64] bf16
  u16* Kb = Qb + (size_t)MROWS * HD;
  u16* Vb = Kb + (size_t)MROWS * HD;
  u16* AO = Vb + (size_t)MROWS * HD;   // [B*S][1024] bf16   (total 88MB)
  u16* Vt = X;                         // reuse X after QKV GEMMs

  dim3 tb(256);
  wtrans_kernel<<<dim3(16, 16), tb, 0, stream>>>(Wq, Wtq);
  wtrans_kernel<<<dim3(16, 16), tb, 0, stream>>>(Wk, Wtk);
  wtrans_kernel<<<dim3(16, 16), tb, 0, stream>>>(Wv, Wtv);
  wtrans_kernel<<<dim3(16, 16), tb, 0, stream>>>(Wo, Wto);

  const int cvtg = MROWS * DIN / 8 / 256;  // 4096
  cvt_kernel<<<dim3(cvtg), tb, 0, stream>>>(q_in, X);
  gemm128_kernel<0><<<dim3(512), tb, 0, stream>>>(X, Wtq, Qb);
  cvt_kernel<<<dim3(cvtg), tb, 0, stream>>>(k_in, X);
  gemm128_kernel<0><<<dim3(512), tb, 0, stream>>>(X, Wtk, Kb);
  cvt_kernel<<<dim3(cvtg), tb, 0, stream>>>(v_in, X);
  gemm128_kernel<0><<<dim3(512), tb, 0, stream>>>(X, Wtv, Vb);

  vtrans_kernel<<<dim3(SEQ / 64, BATCH * HEADS), tb, 0, stream>>>(Vb, Vt);

  attn_kernel<<<dim3(2048), tb, 0, stream>>>(Qb, Kb, Vt, AO);

  gemm128_kernel<1><<<dim3(512), tb, 0, stream>>>(AO, Wto, out);
}

// Round 7
// 298.762 us; speedup vs baseline: 1.5138x; 1.0082x over previous
//
#include <hip/hip_runtime.h>
#include <hip/hip_bf16.h>

// MHA: cvt->proj(QKV via DMA-staged MFMA GEMM) -> flash attention -> out proj.
// R7 = R3 (last passing) + ones-MFMA l-sum + max3 tree (register-only deltas).
#define DIN   1024
#define HEADS 16
#define DK    64
#define BATCH 4
#define SEQ   2048
#define MROWS (BATCH*SEQ)   /* 8192 */
#define HD    (HEADS*DK)    /* 1024 */

typedef unsigned short u16;
typedef unsigned int   u32;
typedef __attribute__((ext_vector_type(8))) short v8s;
typedef __attribute__((ext_vector_type(4))) float v4f;

__device__ __forceinline__ u16 f2bf(float x) {
  union { float f; u32 u; } v; v.f = x;
  u32 r = v.u + 0x7FFFu + ((v.u >> 16) & 1u);
  return (u16)(r >> 16);
}
__device__ __forceinline__ int cvtpk(float lo, float hi) {
  int r;
  asm("v_cvt_pk_bf16_f32 %0, %1, %2" : "=v"(r) : "v"(lo), "v"(hi));
  return r;
}
__device__ __forceinline__ float max3f(float a, float b, float c) {
  float r;
  asm("v_max3_f32 %0, %1, %2, %3" : "=v"(r) : "v"(a), "v"(b), "v"(c));
  return r;
}
__device__ __forceinline__ void gload16(const void* g, void* l) {
  __builtin_amdgcn_global_load_lds(
      (__attribute__((address_space(1))) void*)(uintptr_t)(g),
      (__attribute__((address_space(3))) void*)(uintptr_t)(l), 16, 0, 0);
}

// ---- weight transpose: W[k][n] f32 -> Wt[n][k] bf16 ----
__global__ __launch_bounds__(256) void wtrans_kernel(const float* __restrict__ in,
                                                     u16* __restrict__ out) {
  __shared__ float tile[64][65];
  int bx = blockIdx.x * 64;
  int by = blockIdx.y * 64;
  for (int i = threadIdx.x; i < 64 * 64; i += 256) {
    int r = i >> 6, c = i & 63;
    tile[r][c] = in[(size_t)(by + r) * DIN + bx + c];
  }
  __syncthreads();
  for (int i = threadIdx.x; i < 64 * 64; i += 256) {
    int r = i >> 6, c = i & 63;
    out[(size_t)(bx + r) * DIN + by + c] = f2bf(tile[c][r]);
  }
}

// ---- f32 -> bf16 convert (8 elems/thread) ----
__global__ __launch_bounds__(256) void cvt_kernel(const float* __restrict__ in,
                                                  u16* __restrict__ out) {
  int i = blockIdx.x * 256 + threadIdx.x;
  const float4* p = (const float4*)(in + (size_t)i * 8);
  float4 a = p[0], b = p[1];
  int4 w;
  w.x = cvtpk(a.x, a.y);
  w.y = cvtpk(a.z, a.w);
  w.z = cvtpk(b.x, b.y);
  w.w = cvtpk(b.z, b.w);
  *(int4*)(out + (size_t)i * 8) = w;
}

// ---- V transpose: Vb[bh][s][d] bf16 -> Vt[bh][d][s] bf16 ----
__global__ __launch_bounds__(256) void vtrans_kernel(const u16* __restrict__ in,
                                                     u16* __restrict__ out) {
  __shared__ u16 t[64][72];
  const int s0 = blockIdx.x * 64;
  const int bh = blockIdx.y;
  const int r = threadIdx.x >> 2;
  const int c = (threadIdx.x & 3) * 16;
  const u16* ip = in + (size_t)bh * SEQ * DK + (size_t)(s0 + r) * DK + c;
  *(int4*)&t[r][c] = ((const int4*)ip)[0];
  *(int4*)&t[r][c + 8] = ((const int4*)ip)[1];
  __syncthreads();
  u16 tmp[16];
#pragma unroll
  for (int j = 0; j < 16; j++) tmp[j] = t[c + j][r];
  u16* op = out + (size_t)bh * DK * SEQ + (size_t)r * SEQ + s0 + c;
  ((int4*)op)[0] = *(int4*)&tmp[0];
  ((int4*)op)[1] = *(int4*)&tmp[8];
}

// ---- 128x128 tile GEMM, K=1024, all-bf16 operands, global_load_lds staging.
// MODE 0: out bf16 scattered to [B,H,S,dk].  MODE 1: out f32 linear. ----
template <int MODE>
__global__ __launch_bounds__(256) void gemm128_kernel(const u16* __restrict__ A,
                                                      const u16* __restrict__ Bt,
                                                      void* __restrict__ Cout) {
  __shared__ u16 A_lds[128][32];  // linear (gload_lds requires it)
  __shared__ u16 B_lds[128][32];
  const int tid = threadIdx.x;
  const int lane = tid & 63;
  const int wv = tid >> 6;
  const int wm = wv & 1, wn = wv >> 1;
  const int bid = blockIdx.x;
  const int swz = (bid & 7) * 64 + (bid >> 3);  // 512 % 8 == 0, bijective
  const int m0 = (swz >> 3) * 128;
  const int n0 = (swz & 7) * 128;
  const int l15 = lane & 15;
  const int k8 = (lane >> 4) * 8;

  const u16* ga = A + (size_t)(m0 + wv * 16 + (lane >> 2)) * DIN + (lane & 3) * 8;
  const u16* gb = Bt + (size_t)(n0 + wv * 16 + (lane >> 2)) * DIN + (lane & 3) * 8;
  u16* la0 = &A_lds[wv * 16][0];
  u16* la1 = &A_lds[wv * 16 + 64][0];
  u16* lb0 = &B_lds[wv * 16][0];
  u16* lb1 = &B_lds[wv * 16 + 64][0];

  v4f acc[4][4];
#pragma unroll
  for (int i = 0; i < 4; i++)
#pragma unroll
    for (int j = 0; j < 4; j++) acc[i][j] = (v4f)0.f;

  for (int kk = 0; kk < DIN; kk += 32) {
    __syncthreads();
    gload16(ga + kk, la0);
    gload16(ga + (size_t)64 * DIN + kk, la1);
    gload16(gb + kk, lb0);
    gload16(gb + (size_t)64 * DIN + kk, lb1);
    __syncthreads();

    v8s a[4], b[4];
#pragma unroll
    for (int mi = 0; mi < 4; mi++) a[mi] = *(const v8s*)&A_lds[wm * 64 + mi * 16 + l15][k8];
#pragma unroll
    for (int ni = 0; ni < 4; ni++) b[ni] = *(const v8s*)&B_lds[wn * 64 + ni * 16 + l15][k8];
#pragma unroll
    for (int mi = 0; mi < 4; mi++)
#pragma unroll
      for (int ni = 0; ni < 4; ni++)
        acc[mi][ni] = __builtin_amdgcn_mfma_f32_16x16x32_bf16(a[mi], b[ni], acc[mi][ni], 0, 0, 0);
  }

  const int grp = lane >> 4;
#pragma unroll
  for (int mi = 0; mi < 4; mi++) {
#pragma unroll
    for (int ni = 0; ni < 4; ni++) {
      if (MODE == 0) {
        int w01 = cvtpk(acc[mi][ni][0], acc[mi][ni][1]);
        int w23 = cvtpk(acc[mi][ni][2], acc[mi][ni][3]);
        u16 h[4] = {(u16)w01, (u16)(w01 >> 16), (u16)w23, (u16)(w23 >> 16)};
#pragma unroll
        for (int r = 0; r < 4; r++) {
          int row = m0 + wm * 64 + mi * 16 + grp * 4 + r;
          int col = n0 + wn * 64 + ni * 16 + l15;
          int bb = row >> 11, ss = row & 2047;
          int hh = col >> 6, dd = col & 63;
          ((u16*)Cout)[((((size_t)bb * HEADS + hh) * SEQ + ss) << 6) + dd] = h[r];
        }
      } else {
#pragma unroll
        for (int r = 0; r < 4; r++) {
          int row = m0 + wm * 64 + mi * 16 + grp * 4 + r;
          int col = n0 + wn * 64 + ni * 16 + l15;
          ((float*)Cout)[(size_t)row * HD + col] = acc[mi][ni][r];
        }
      }
    }
  }
}

// ---- flash attention (swapped QK^T, log2 domain, defer-max, MFMA l-sum) ----
__global__ __launch_bounds__(256) void attn_kernel(const u16* __restrict__ Q,
                                                   const u16* __restrict__ Kmat,
                                                   const u16* __restrict__ Vt,
                                                   u16* __restrict__ AO) {
  __shared__ u16 K_lds[64][72];
  __shared__ u16 Vt_lds[64][72];
  __shared__ u16 P_lds[4][16][72];

  const int tid = threadIdx.x;
  const int lane = tid & 63;
  const int wv = tid >> 6;
  const int l15 = lane & 15;
  const int grp = lane >> 4;
  const int k8 = grp * 8;

  const int bid = blockIdx.x;
  const int swz = (bid & 7) * 256 + (bid >> 3);  // XCD: 8 bh per XCD -> K/V L2-fit
  const int bh = swz >> 5;
  const int qt = swz & 31;
  const size_t base = (size_t)bh * SEQ * DK;

  // Q pre-scaled by (1/sqrt(64)) * log2(e) -> scores in log2 domain
  v8s qf[2];
  {
    const int q = qt * 64 + wv * 16 + l15;
    const u16* qp = Q + base + (size_t)q * DK;
    qf[0] = *(const v8s*)(qp + k8);
    qf[1] = *(const v8s*)(qp + 32 + k8);
    const float SCL = 0.125f * 1.44269504f;
#pragma unroll
    for (int j = 0; j < 8; j++) {
      union { float f; u32 u; } a;
      a.u = ((u32)(u16)qf[0][j]) << 16; a.f *= SCL; qf[0][j] = (short)f2bf(a.f);
      a.u = ((u32)(u16)qf[1][j]) << 16; a.f *= SCL; qf[1][j] = (short)f2bf(a.f);
    }
  }

  v8s ones;
#pragma unroll
  for (int j = 0; j < 8; j++) ones[j] = (short)0x3F80;  // bf16 1.0

  float mrow = -1e30f;
  v4f oacc[5];  // [0..3]: O^T d-blocks; [4]: l row-sum via ones-MFMA
#pragma unroll
  for (int db = 0; db < 5; db++) oacc[db] = (v4f)0.f;

  const int srow = tid >> 2;
  const int sc16 = (tid & 3) * 16;

  for (int t = 0; t < SEQ / 64; ++t) {
    __syncthreads();
    {
      const u16* kp = Kmat + base + (size_t)(t * 64 + srow) * DK + sc16;
      *(int4*)&K_lds[srow][sc16] = ((const int4*)kp)[0];
      *(int4*)&K_lds[srow][sc16 + 8] = ((const int4*)kp)[1];
      const u16* vp = Vt + base + (size_t)srow * SEQ + t * 64 + sc16;
      *(int4*)&Vt_lds[srow][sc16] = ((const int4*)vp)[0];
      *(int4*)&Vt_lds[srow][sc16 + 8] = ((const int4*)vp)[1];
    }
    __syncthreads();

    // S^T[key][q] = K · Q^T
    v4f sacc[4];
#pragma unroll
    for (int kb = 0; kb < 4; kb++) sacc[kb] = (v4f)0.f;
    __builtin_amdgcn_s_setprio(1);
#pragma unroll
    for (int ks = 0; ks < 2; ks++)
#pragma unroll
      for (int kb = 0; kb < 4; kb++) {
        v8s kf = *(const v8s*)&K_lds[kb * 16 + l15][ks * 32 + k8];
        sacc[kb] = __builtin_amdgcn_mfma_f32_16x16x32_bf16(kf, qf[ks], sacc[kb], 0, 0, 0);
      }
    __builtin_amdgcn_s_setprio(0);

    // row max: max3 tree (16 -> 1 in 8 ops) then cross-lane over grp
    float m1 = max3f(sacc[0][0], sacc[0][1], sacc[0][2]);
    float m2 = max3f(sacc[0][3], sacc[1][0], sacc[1][1]);
    float m3 = max3f(sacc[1][2], sacc[1][3], sacc[2][0]);
    float m4 = max3f(sacc[2][1], sacc[2][2], sacc[2][3]);
    float m5 = max3f(sacc[3][0], sacc[3][1], sacc[3][2]);
    float mx = fmaxf(max3f(m1, m2, m3), max3f(m4, m5, sacc[3][3]));
    mx = fmaxf(mx, __shfl_xor(mx, 16));
    mx = fmaxf(mx, __shfl_xor(mx, 32));
    // defer-max: rescale only when max grew > 8 (log2 domain; P <= 256)
    if (__any(mx - mrow > 8.f)) {
      float mnew = fmaxf(mrow, mx);
      float fac = __builtin_amdgcn_exp2f(mrow - mnew);
#pragma unroll
      for (int db = 0; db < 5; db++) oacc[db] *= fac;
      mrow = mnew;
    }
    // exp2; P^T -> per-wave LDS (b64 writes, cvt_pk packed); l via MFMA below
    float p[4][4];
#pragma unroll
    for (int kb = 0; kb < 4; kb++)
#pragma unroll
      for (int r = 0; r < 4; r++)
        p[kb][r] = __builtin_amdgcn_exp2f(sacc[kb][r] - mrow);
#pragma unroll
    for (int kb = 0; kb < 4; kb++) {
      int2 w;
      w.x = cvtpk(p[kb][0], p[kb][1]);
      w.y = cvtpk(p[kb][2], p[kb][3]);
      *(int2*)&P_lds[wv][l15][kb * 16 + grp * 4] = w;
    }
    asm volatile("s_waitcnt lgkmcnt(0)" ::: "memory");

    // O^T += V^T · P^T ; 5th block (A=ones) accumulates l in the matrix pipe
    __builtin_amdgcn_s_setprio(1);
#pragma unroll
    for (int ks = 0; ks < 2; ks++) {
      v8s pf = *(const v8s*)&P_lds[wv][l15][ks * 32 + k8];
#pragma unroll
      for (int db = 0; db < 4; db++) {
        v8s vf = *(const v8s*)&Vt_lds[db * 16 + l15][ks * 32 + k8];
        oacc[db] = __builtin_amdgcn_mfma_f32_16x16x32_bf16(vf, pf, oacc[db], 0, 0, 0);
      }
      oacc[4] = __builtin_amdgcn_mfma_f32_16x16x32_bf16(ones, pf, oacc[4], 0, 0, 0);
    }
    __builtin_amdgcn_s_setprio(0);
  }

  const int bb = bh >> 4, hh = bh & 15;
  const int q = qt * 64 + wv * 16 + l15;
  const float inv = 1.0f / oacc[4][0];
  const size_t rowbase = ((size_t)bb * SEQ + q) * HD + hh * DK;
#pragma unroll
  for (int db = 0; db < 4; db++) {
    int2 w;
    w.x = cvtpk(oacc[db][0] * inv, oacc[db][1] * inv);
    w.y = cvtpk(oacc[db][2] * inv, oacc[db][3] * inv);
    *(int2*)&AO[rowbase + db * 16 + grp * 4] = w;
  }
}

extern "C" void kernel_launch(void* const* d_in, const int* in_sizes, int n_in,
                              void* d_out, int out_size, void* d_ws, size_t ws_size,
                              hipStream_t stream) {
  const float* q_in = (const float*)d_in[0];
  const float* k_in = (const float*)d_in[1];
  const float* v_in = (const float*)d_in[2];
  const float* Wq = (const float*)d_in[3];
  const float* Wk = (const float*)d_in[4];
  const float* Wv = (const float*)d_in[5];
  const float* Wo = (const float*)d_in[6];
  float* out = (float*)d_out;

  u16* ws = (u16*)d_ws;
  const size_t M1 = (size_t)1 << 20;
  u16* Wtq = ws;             // 4 x [1024][1024] bf16 (8MB)
  u16* Wtk = Wtq + M1;
  u16* Wtv = Wtk + M1;
  u16* Wto = Wtv + M1;
  u16* X  = Wto + M1;                  // 16MB scratch: bf16 activations / Vt
  u16* Qb = X + (size_t)MROWS * DIN;   // [B*H][S][64] bf16
  u16* Kb = Qb + (size_t)MROWS * HD;
  u16* Vb = Kb + (size_t)MROWS * HD;
  u16* AO = Vb + (size_t)MROWS * HD;   // [B*S][1024] bf16   (total 88MB)
  u16* Vt = X;                         // reuse X after QKV GEMMs

  dim3 tb(256);
  wtrans_kernel<<<dim3(16, 16), tb, 0, stream>>>(Wq, Wtq);
  wtrans_kernel<<<dim3(16, 16), tb, 0, stream>>>(Wk, Wtk);
  wtrans_kernel<<<dim3(16, 16), tb, 0, stream>>>(Wv, Wtv);
  wtrans_kernel<<<dim3(16, 16), tb, 0, stream>>>(Wo, Wto);

  const int cvtg = MROWS * DIN / 8 / 256;  // 4096
  cvt_kernel<<<dim3(cvtg), tb, 0, stream>>>(q_in, X);
  gemm128_kernel<0><<<dim3(512), tb, 0, stream>>>(X, Wtq, Qb);
  cvt_kernel<<<dim3(cvtg), tb, 0, stream>>>(k_in, X);
  gemm128_kernel<0><<<dim3(512), tb, 0, stream>>>(X, Wtk, Kb);
  cvt_kernel<<<dim3(cvtg), tb, 0, stream>>>(v_in, X);
  gemm128_kernel<0><<<dim3(512), tb, 0, stream>>>(X, Wtv, Vb);

  vtrans_kernel<<<dim3(SEQ / 64, BATCH * HEADS), tb, 0, stream>>>(Vb, Vt);

  attn_kernel<<<dim3(2048), tb, 0, stream>>>(Qb, Kb, Vt, AO);

  gemm128_kernel<1><<<dim3(512), tb, 0, stream>>>(AO, Wto, out);
}

// Round 8
// 271.515 us; speedup vs baseline: 1.6657x; 1.1004x over previous
//
#include <hip/hip_runtime.h>
#include <hip/hip_bf16.h>

// MHA: cvt->proj(QKV via DMA-staged MFMA GEMM) -> flash attention -> out proj.
// R8 = R7 + attn K/V reg-staged XOR-swizzled LDS (m214 pattern) + merged wtrans.
#define DIN   1024
#define HEADS 16
#define DK    64
#define BATCH 4
#define SEQ   2048
#define MROWS (BATCH*SEQ)   /* 8192 */
#define HD    (HEADS*DK)    /* 1024 */

typedef unsigned short u16;
typedef unsigned int   u32;
typedef __attribute__((ext_vector_type(8))) short v8s;
typedef __attribute__((ext_vector_type(4))) float v4f;

__device__ __forceinline__ u16 f2bf(float x) {
  union { float f; u32 u; } v; v.f = x;
  u32 r = v.u + 0x7FFFu + ((v.u >> 16) & 1u);
  return (u16)(r >> 16);
}
__device__ __forceinline__ int cvtpk(float lo, float hi) {
  int r;
  asm("v_cvt_pk_bf16_f32 %0, %1, %2" : "=v"(r) : "v"(lo), "v"(hi));
  return r;
}
__device__ __forceinline__ float max3f(float a, float b, float c) {
  float r;
  asm("v_max3_f32 %0, %1, %2, %3" : "=v"(r) : "v"(a), "v"(b), "v"(c));
  return r;
}
__device__ __forceinline__ void gload16(const void* g, void* l) {
  __builtin_amdgcn_global_load_lds(
      (__attribute__((address_space(1))) void*)(uintptr_t)(g),
      (__attribute__((address_space(3))) void*)(uintptr_t)(l), 16, 0, 0);
}
// swizzled access into flat [64 rows][8 units of 16B] tile: phys unit = u ^ (row&7)
__device__ __forceinline__ v8s lds_read_swz(const u16* base, int row, int unit) {
  return *(const v8s*)((const char*)base + (row << 7) + (((unit) ^ (row & 7)) << 4));
}

// ---- weight transpose x4: W[k][n] f32 -> Wt[n][k] bf16 ----
__global__ __launch_bounds__(256) void wtrans4_kernel(
    const float* __restrict__ w0, const float* __restrict__ w1,
    const float* __restrict__ w2, const float* __restrict__ w3,
    u16* __restrict__ o0, u16* __restrict__ o1,
    u16* __restrict__ o2, u16* __restrict__ o3) {
  __shared__ float tile[64][65];
  const float* in = blockIdx.z == 0 ? w0 : blockIdx.z == 1 ? w1 : blockIdx.z == 2 ? w2 : w3;
  u16* out = blockIdx.z == 0 ? o0 : blockIdx.z == 1 ? o1 : blockIdx.z == 2 ? o2 : o3;
  int bx = blockIdx.x * 64;
  int by = blockIdx.y * 64;
  for (int i = threadIdx.x; i < 64 * 64; i += 256) {
    int r = i >> 6, c = i & 63;
    tile[r][c] = in[(size_t)(by + r) * DIN + bx + c];
  }
  __syncthreads();
  for (int i = threadIdx.x; i < 64 * 64; i += 256) {
    int r = i >> 6, c = i & 63;
    out[(size_t)(bx + r) * DIN + by + c] = f2bf(tile[c][r]);
  }
}

// ---- f32 -> bf16 convert (8 elems/thread) ----
__global__ __launch_bounds__(256) void cvt_kernel(const float* __restrict__ in,
                                                  u16* __restrict__ out) {
  int i = blockIdx.x * 256 + threadIdx.x;
  const float4* p = (const float4*)(in + (size_t)i * 8);
  float4 a = p[0], b = p[1];
  int4 w;
  w.x = cvtpk(a.x, a.y);
  w.y = cvtpk(a.z, a.w);
  w.z = cvtpk(b.x, b.y);
  w.w = cvtpk(b.z, b.w);
  *(int4*)(out + (size_t)i * 8) = w;
}

// ---- V transpose: Vb[bh][s][d] bf16 -> Vt[bh][d][s] bf16 ----
__global__ __launch_bounds__(256) void vtrans_kernel(const u16* __restrict__ in,
                                                     u16* __restrict__ out) {
  __shared__ u16 t[64][72];
  const int s0 = blockIdx.x * 64;
  const int bh = blockIdx.y;
  const int r = threadIdx.x >> 2;
  const int c = (threadIdx.x & 3) * 16;
  const u16* ip = in + (size_t)bh * SEQ * DK + (size_t)(s0 + r) * DK + c;
  *(int4*)&t[r][c] = ((const int4*)ip)[0];
  *(int4*)&t[r][c + 8] = ((const int4*)ip)[1];
  __syncthreads();
  u16 tmp[16];
#pragma unroll
  for (int j = 0; j < 16; j++) tmp[j] = t[c + j][r];
  u16* op = out + (size_t)bh * DK * SEQ + (size_t)r * SEQ + s0 + c;
  ((int4*)op)[0] = *(int4*)&tmp[0];
  ((int4*)op)[1] = *(int4*)&tmp[8];
}

// ---- 128x128 tile GEMM, K=1024, all-bf16 operands, global_load_lds staging.
// MODE 0: out bf16 scattered to [B,H,S,dk].  MODE 1: out f32 linear. ----
template <int MODE>
__global__ __launch_bounds__(256) void gemm128_kernel(const u16* __restrict__ A,
                                                      const u16* __restrict__ Bt,
                                                      void* __restrict__ Cout) {
  __shared__ u16 A_lds[128][32];  // linear (gload_lds requires it)
  __shared__ u16 B_lds[128][32];
  const int tid = threadIdx.x;
  const int lane = tid & 63;
  const int wv = tid >> 6;
  const int wm = wv & 1, wn = wv >> 1;
  const int bid = blockIdx.x;
  const int swz = (bid & 7) * 64 + (bid >> 3);  // 512 % 8 == 0, bijective
  const int m0 = (swz >> 3) * 128;
  const int n0 = (swz & 7) * 128;
  const int l15 = lane & 15;
  const int k8 = (lane >> 4) * 8;

  const u16* ga = A + (size_t)(m0 + wv * 16 + (lane >> 2)) * DIN + (lane & 3) * 8;
  const u16* gb = Bt + (size_t)(n0 + wv * 16 + (lane >> 2)) * DIN + (lane & 3) * 8;
  u16* la0 = &A_lds[wv * 16][0];
  u16* la1 = &A_lds[wv * 16 + 64][0];
  u16* lb0 = &B_lds[wv * 16][0];
  u16* lb1 = &B_lds[wv * 16 + 64][0];

  v4f acc[4][4];
#pragma unroll
  for (int i = 0; i < 4; i++)
#pragma unroll
    for (int j = 0; j < 4; j++) acc[i][j] = (v4f)0.f;

  for (int kk = 0; kk < DIN; kk += 32) {
    __syncthreads();
    gload16(ga + kk, la0);
    gload16(ga + (size_t)64 * DIN + kk, la1);
    gload16(gb + kk, lb0);
    gload16(gb + (size_t)64 * DIN + kk, lb1);
    __syncthreads();

    v8s a[4], b[4];
#pragma unroll
    for (int mi = 0; mi < 4; mi++) a[mi] = *(const v8s*)&A_lds[wm * 64 + mi * 16 + l15][k8];
#pragma unroll
    for (int ni = 0; ni < 4; ni++) b[ni] = *(const v8s*)&B_lds[wn * 64 + ni * 16 + l15][k8];
#pragma unroll
    for (int mi = 0; mi < 4; mi++)
#pragma unroll
      for (int ni = 0; ni < 4; ni++)
        acc[mi][ni] = __builtin_amdgcn_mfma_f32_16x16x32_bf16(a[mi], b[ni], acc[mi][ni], 0, 0, 0);
  }

  const int grp = lane >> 4;
#pragma unroll
  for (int mi = 0; mi < 4; mi++) {
#pragma unroll
    for (int ni = 0; ni < 4; ni++) {
      if (MODE == 0) {
        int w01 = cvtpk(acc[mi][ni][0], acc[mi][ni][1]);
        int w23 = cvtpk(acc[mi][ni][2], acc[mi][ni][3]);
        u16 h[4] = {(u16)w01, (u16)(w01 >> 16), (u16)w23, (u16)(w23 >> 16)};
#pragma unroll
        for (int r = 0; r < 4; r++) {
          int row = m0 + wm * 64 + mi * 16 + grp * 4 + r;
          int col = n0 + wn * 64 + ni * 16 + l15;
          int bb = row >> 11, ss = row & 2047;
          int hh = col >> 6, dd = col & 63;
          ((u16*)Cout)[((((size_t)bb * HEADS + hh) * SEQ + ss) << 6) + dd] = h[r];
        }
      } else {
#pragma unroll
        for (int r = 0; r < 4; r++) {
          int row = m0 + wm * 64 + mi * 16 + grp * 4 + r;
          int col = n0 + wn * 64 + ni * 16 + l15;
          ((float*)Cout)[(size_t)row * HD + col] = acc[mi][ni][r];
        }
      }
    }
  }
}

// ---- flash attention: swapped QK^T, XOR-swizzled reg-staged K/V LDS,
//      log2 domain, defer-max, ones-MFMA l-sum ----
__global__ __launch_bounds__(256) void attn_kernel(const u16* __restrict__ Q,
                                                   const u16* __restrict__ Kmat,
                                                   const u16* __restrict__ Vt,
                                                   u16* __restrict__ AO) {
  __shared__ u16 K_lds[64 * 64];   // [key][d] swizzled, 128B rows
  __shared__ u16 V_lds[64 * 64];   // [d][key] swizzled
  __shared__ u16 P_lds[4][16][72]; // per-wave P^T, padded linear (as R7)

  const int tid = threadIdx.x;
  const int lane = tid & 63;
  const int wv = tid >> 6;
  const int l15 = lane & 15;
  const int grp = lane >> 4;
  const int k8 = grp * 8;

  const int bid = blockIdx.x;
  const int swz = (bid & 7) * 256 + (bid >> 3);  // XCD: 8 bh per XCD -> K/V L2-fit
  const int bh = swz >> 5;
  const int qt = swz & 31;
  const size_t base = (size_t)bh * SEQ * DK;

  // Q pre-scaled by (1/sqrt(64)) * log2(e) -> scores in log2 domain
  v8s qf[2];
  {
    const int q = qt * 64 + wv * 16 + l15;
    const u16* qp = Q + base + (size_t)q * DK;
    qf[0] = *(const v8s*)(qp + k8);
    qf[1] = *(const v8s*)(qp + 32 + k8);
    const float SCL = 0.125f * 1.44269504f;
#pragma unroll
    for (int j = 0; j < 8; j++) {
      union { float f; u32 u; } a;
      a.u = ((u32)(u16)qf[0][j]) << 16; a.f *= SCL; qf[0][j] = (short)f2bf(a.f);
      a.u = ((u32)(u16)qf[1][j]) << 16; a.f *= SCL; qf[1][j] = (short)f2bf(a.f);
    }
  }

  v8s ones;
#pragma unroll
  for (int j = 0; j < 8; j++) ones[j] = (short)0x3F80;  // bf16 1.0

  float mrow = -1e30f;
  v4f oacc[5];  // [0..3]: O^T d-blocks; [4]: l row-sum via ones-MFMA
#pragma unroll
  for (int db = 0; db < 5; db++) oacc[db] = (v4f)0.f;

  const int srow = tid >> 2;     // 0..63
  const int a3 = tid & 3;        // 32B chunk within 128B row
  const int sw = srow & 7;
  u16* krow = &K_lds[srow << 6];
  u16* vrow = &V_lds[srow << 6];

  for (int t = 0; t < SEQ / 64; ++t) {
    __syncthreads();
    {
      // global loads linear/coalesced; stores XOR-swizzled (unit ^= row&7)
      const u16* kp = Kmat + base + (size_t)(t * 64 + srow) * DK + a3 * 16;
      const u16* vp = Vt + base + (size_t)srow * SEQ + t * 64 + a3 * 16;
      int4 k0 = ((const int4*)kp)[0];
      int4 k1 = ((const int4*)kp)[1];
      int4 v0 = ((const int4*)vp)[0];
      int4 v1 = ((const int4*)vp)[1];
      *(int4*)((char*)krow + (((2 * a3 + 0) ^ sw) << 4)) = k0;
      *(int4*)((char*)krow + (((2 * a3 + 1) ^ sw) << 4)) = k1;
      *(int4*)((char*)vrow + (((2 * a3 + 0) ^ sw) << 4)) = v0;
      *(int4*)((char*)vrow + (((2 * a3 + 1) ^ sw) << 4)) = v1;
    }
    __syncthreads();

    // S^T[key][q] = K · Q^T
    v4f sacc[4];
#pragma unroll
    for (int kb = 0; kb < 4; kb++) sacc[kb] = (v4f)0.f;
    __builtin_amdgcn_s_setprio(1);
#pragma unroll
    for (int ks = 0; ks < 2; ks++)
#pragma unroll
      for (int kb = 0; kb < 4; kb++) {
        v8s kf = lds_read_swz(K_lds, kb * 16 + l15, ks * 4 + grp);
        sacc[kb] = __builtin_amdgcn_mfma_f32_16x16x32_bf16(kf, qf[ks], sacc[kb], 0, 0, 0);
      }
    __builtin_amdgcn_s_setprio(0);

    // row max: max3 tree (16 -> 1 in 8 ops) then cross-lane over grp
    float m1 = max3f(sacc[0][0], sacc[0][1], sacc[0][2]);
    float m2 = max3f(sacc[0][3], sacc[1][0], sacc[1][1]);
    float m3 = max3f(sacc[1][2], sacc[1][3], sacc[2][0]);
    float m4 = max3f(sacc[2][1], sacc[2][2], sacc[2][3]);
    float m5 = max3f(sacc[3][0], sacc[3][1], sacc[3][2]);
    float mx = fmaxf(max3f(m1, m2, m3), max3f(m4, m5, sacc[3][3]));
    mx = fmaxf(mx, __shfl_xor(mx, 16));
    mx = fmaxf(mx, __shfl_xor(mx, 32));
    // defer-max: rescale only when max grew > 8 (log2 domain; P <= 256)
    if (__any(mx - mrow > 8.f)) {
      float mnew = fmaxf(mrow, mx);
      float fac = __builtin_amdgcn_exp2f(mrow - mnew);
#pragma unroll
      for (int db = 0; db < 5; db++) oacc[db] *= fac;
      mrow = mnew;
    }
    // exp2; P^T -> per-wave LDS (b64 writes, cvt_pk packed); l via MFMA below
    float p[4][4];
#pragma unroll
    for (int kb = 0; kb < 4; kb++)
#pragma unroll
      for (int r = 0; r < 4; r++)
        p[kb][r] = __builtin_amdgcn_exp2f(sacc[kb][r] - mrow);
#pragma unroll
    for (int kb = 0; kb < 4; kb++) {
      int2 w;
      w.x = cvtpk(p[kb][0], p[kb][1]);
      w.y = cvtpk(p[kb][2], p[kb][3]);
      *(int2*)&P_lds[wv][l15][kb * 16 + grp * 4] = w;
    }
    asm volatile("s_waitcnt lgkmcnt(0)" ::: "memory");

    // O^T += V^T · P^T ; 5th block (A=ones) accumulates l in the matrix pipe
    __builtin_amdgcn_s_setprio(1);
#pragma unroll
    for (int ks = 0; ks < 2; ks++) {
      v8s pf = *(const v8s*)&P_lds[wv][l15][ks * 32 + k8];
#pragma unroll
      for (int db = 0; db < 4; db++) {
        v8s vf = lds_read_swz(V_lds, db * 16 + l15, ks * 4 + grp);
        oacc[db] = __builtin_amdgcn_mfma_f32_16x16x32_bf16(vf, pf, oacc[db], 0, 0, 0);
      }
      oacc[4] = __builtin_amdgcn_mfma_f32_16x16x32_bf16(ones, pf, oacc[4], 0, 0, 0);
    }
    __builtin_amdgcn_s_setprio(0);
  }

  const int bb = bh >> 4, hh = bh & 15;
  const int q = qt * 64 + wv * 16 + l15;
  const float inv = 1.0f / oacc[4][0];
  const size_t rowbase = ((size_t)bb * SEQ + q) * HD + hh * DK;
#pragma unroll
  for (int db = 0; db < 4; db++) {
    int2 w;
    w.x = cvtpk(oacc[db][0] * inv, oacc[db][1] * inv);
    w.y = cvtpk(oacc[db][2] * inv, oacc[db][3] * inv);
    *(int2*)&AO[rowbase + db * 16 + grp * 4] = w;
  }
}

extern "C" void kernel_launch(void* const* d_in, const int* in_sizes, int n_in,
                              void* d_out, int out_size, void* d_ws, size_t ws_size,
                              hipStream_t stream) {
  const float* q_in = (const float*)d_in[0];
  const float* k_in = (const float*)d_in[1];
  const float* v_in = (const float*)d_in[2];
  const float* Wq = (const float*)d_in[3];
  const float* Wk = (const float*)d_in[4];
  const float* Wv = (const float*)d_in[5];
  const float* Wo = (const float*)d_in[6];
  float* out = (float*)d_out;

  u16* ws = (u16*)d_ws;
  const size_t M1 = (size_t)1 << 20;
  u16* Wtq = ws;             // 4 x [1024][1024] bf16 (8MB)
  u16* Wtk = Wtq + M1;
  u16* Wtv = Wtk + M1;
  u16* Wto = Wtv + M1;
  u16* X  = Wto + M1;                  // 16MB scratch: bf16 activations / Vt
  u16* Qb = X + (size_t)MROWS * DIN;   // [B*H][S][64] bf16
  u16* Kb = Qb + (size_t)MROWS * HD;
  u16* Vb = Kb + (size_t)MROWS * HD;
  u16* AO = Vb + (size_t)MROWS * HD;   // [B*S][1024] bf16   (total 88MB)
  u16* Vt = X;                         // reuse X after QKV GEMMs

  dim3 tb(256);
  wtrans4_kernel<<<dim3(16, 16, 4), tb, 0, stream>>>(Wq, Wk, Wv, Wo, Wtq, Wtk, Wtv, Wto);

  const int cvtg = MROWS * DIN / 8 / 256;  // 4096
  cvt_kernel<<<dim3(cvtg), tb, 0, stream>>>(q_in, X);
  gemm128_kernel<0><<<dim3(512), tb, 0, stream>>>(X, Wtq, Qb);
  cvt_kernel<<<dim3(cvtg), tb, 0, stream>>>(k_in, X);
  gemm128_kernel<0><<<dim3(512), tb, 0, stream>>>(X, Wtk, Kb);
  cvt_kernel<<<dim3(cvtg), tb, 0, stream>>>(v_in, X);
  gemm128_kernel<0><<<dim3(512), tb, 0, stream>>>(X, Wtv, Vb);

  vtrans_kernel<<<dim3(SEQ / 64, BATCH * HEADS), tb, 0, stream>>>(Vb, Vt);

  attn_kernel<<<dim3(2048), tb, 0, stream>>>(Qb, Kb, Vt, AO);

  gemm128_kernel<1><<<dim3(512), tb, 0, stream>>>(AO, Wto, out);
}

// Round 9
// 259.761 us; speedup vs baseline: 1.7411x; 1.0453x over previous
//
#include <hip/hip_runtime.h>
#include <hip/hip_bf16.h>

// MHA: cvt->proj(QKV via DMA dbuf MFMA GEMM) -> flash attention (reg-staged
// swizzled dbuf K/V, single barrier/tile) -> out proj.
#define DIN   1024
#define HEADS 16
#define DK    64
#define BATCH 4
#define SEQ   2048
#define MROWS (BATCH*SEQ)   /* 8192 */
#define HD    (HEADS*DK)    /* 1024 */

typedef unsigned short u16;
typedef unsigned int   u32;
typedef __attribute__((ext_vector_type(8))) short v8s;
typedef __attribute__((ext_vector_type(4))) float v4f;

__device__ __forceinline__ u16 f2bf(float x) {
  union { float f; u32 u; } v; v.f = x;
  u32 r = v.u + 0x7FFFu + ((v.u >> 16) & 1u);
  return (u16)(r >> 16);
}
__device__ __forceinline__ int cvtpk(float lo, float hi) {
  int r;
  asm("v_cvt_pk_bf16_f32 %0, %1, %2" : "=v"(r) : "v"(lo), "v"(hi));
  return r;
}
__device__ __forceinline__ float max3f(float a, float b, float c) {
  float r;
  asm("v_max3_f32 %0, %1, %2, %3" : "=v"(r) : "v"(a), "v"(b), "v"(c));
  return r;
}
__device__ __forceinline__ void gload16(const void* g, void* l) {
  __builtin_amdgcn_global_load_lds(
      (__attribute__((address_space(1))) void*)(uintptr_t)(g),
      (__attribute__((address_space(3))) void*)(uintptr_t)(l), 16, 0, 0);
}
// swizzled access into flat [64 rows][8 units of 16B] tile: phys unit = u ^ (row&7)
__device__ __forceinline__ v8s lds_read_swz(const u16* base, int row, int unit) {
  return *(const v8s*)((const char*)base + (row << 7) + (((unit) ^ (row & 7)) << 4));
}

// ---- weight transpose x4: W[k][n] f32 -> Wt[n][k] bf16 ----
__global__ __launch_bounds__(256) void wtrans4_kernel(
    const float* __restrict__ w0, const float* __restrict__ w1,
    const float* __restrict__ w2, const float* __restrict__ w3,
    u16* __restrict__ o0, u16* __restrict__ o1,
    u16* __restrict__ o2, u16* __restrict__ o3) {
  __shared__ float tile[64][65];
  const float* in = blockIdx.z == 0 ? w0 : blockIdx.z == 1 ? w1 : blockIdx.z == 2 ? w2 : w3;
  u16* out = blockIdx.z == 0 ? o0 : blockIdx.z == 1 ? o1 : blockIdx.z == 2 ? o2 : o3;
  int bx = blockIdx.x * 64;
  int by = blockIdx.y * 64;
  for (int i = threadIdx.x; i < 64 * 64; i += 256) {
    int r = i >> 6, c = i & 63;
    tile[r][c] = in[(size_t)(by + r) * DIN + bx + c];
  }
  __syncthreads();
  for (int i = threadIdx.x; i < 64 * 64; i += 256) {
    int r = i >> 6, c = i & 63;
    out[(size_t)(bx + r) * DIN + by + c] = f2bf(tile[c][r]);
  }
}

// ---- f32 -> bf16 convert (8 elems/thread) ----
__global__ __launch_bounds__(256) void cvt_kernel(const float* __restrict__ in,
                                                  u16* __restrict__ out) {
  int i = blockIdx.x * 256 + threadIdx.x;
  const float4* p = (const float4*)(in + (size_t)i * 8);
  float4 a = p[0], b = p[1];
  int4 w;
  w.x = cvtpk(a.x, a.y);
  w.y = cvtpk(a.z, a.w);
  w.z = cvtpk(b.x, b.y);
  w.w = cvtpk(b.z, b.w);
  *(int4*)(out + (size_t)i * 8) = w;
}

// ---- V transpose: Vb[bh][s][d] bf16 -> Vt[bh][d][s] bf16 ----
__global__ __launch_bounds__(256) void vtrans_kernel(const u16* __restrict__ in,
                                                     u16* __restrict__ out) {
  __shared__ u16 t[64][72];
  const int s0 = blockIdx.x * 64;
  const int bh = blockIdx.y;
  const int r = threadIdx.x >> 2;
  const int c = (threadIdx.x & 3) * 16;
  const u16* ip = in + (size_t)bh * SEQ * DK + (size_t)(s0 + r) * DK + c;
  *(int4*)&t[r][c] = ((const int4*)ip)[0];
  *(int4*)&t[r][c + 8] = ((const int4*)ip)[1];
  __syncthreads();
  u16 tmp[16];
#pragma unroll
  for (int j = 0; j < 16; j++) tmp[j] = t[c + j][r];
  u16* op = out + (size_t)bh * DK * SEQ + (size_t)r * SEQ + s0 + c;
  ((int4*)op)[0] = *(int4*)&tmp[0];
  ((int4*)op)[1] = *(int4*)&tmp[8];
}

// ---- 128x128 GEMM, K=1024, bf16, DMA double-buffer, 1 barrier / K-step.
// MODE 0: out bf16 scattered to [B,H,S,dk].  MODE 1: out f32 linear. ----
template <int MODE>
__global__ __launch_bounds__(256) void gemm128_kernel(const u16* __restrict__ A,
                                                      const u16* __restrict__ Bt,
                                                      void* __restrict__ Cout) {
  __shared__ u16 A_lds[2][128 * 32];
  __shared__ u16 B_lds[2][128 * 32];
  const int tid = threadIdx.x;
  const int lane = tid & 63;
  const int wv = tid >> 6;
  const int wm = wv & 1, wn = wv >> 1;
  const int bid = blockIdx.x;
  const int swz = (bid & 7) * 64 + (bid >> 3);  // 512 % 8 == 0, bijective
  const int m0 = (swz >> 3) * 128;
  const int n0 = (swz & 7) * 128;
  const int l15 = lane & 15;
  const int k8 = (lane >> 4) * 8;

  const u16* ga = A + (size_t)(m0 + wv * 16 + (lane >> 2)) * DIN + (lane & 3) * 8;
  const u16* gb = Bt + (size_t)(n0 + wv * 16 + (lane >> 2)) * DIN + (lane & 3) * 8;

  v4f acc[4][4];
#pragma unroll
  for (int i = 0; i < 4; i++)
#pragma unroll
    for (int j = 0; j < 4; j++) acc[i][j] = (v4f)0.f;

#define G_STAGE(ks, b)                                              \
  do {                                                              \
    gload16(ga + (ks) * 32, &A_lds[b][wv * 512]);                   \
    gload16(ga + (size_t)64 * DIN + (ks) * 32, &A_lds[b][wv * 512 + 2048]); \
    gload16(gb + (ks) * 32, &B_lds[b][wv * 512]);                   \
    gload16(gb + (size_t)64 * DIN + (ks) * 32, &B_lds[b][wv * 512 + 2048]); \
  } while (0)

  G_STAGE(0, 0);
  __syncthreads();  // tile 0 landed (vmcnt(0) drain in syncthreads)
  for (int ks = 0; ks < 32; ++ks) {
    const int buf = ks & 1;
    // fragment reads first (so compiler needn't order them vs the new DMA)
    v8s a[4], b[4];
#pragma unroll
    for (int mi = 0; mi < 4; mi++)
      a[mi] = *(const v8s*)&A_lds[buf][(wm * 64 + mi * 16 + l15) * 32 + k8];
#pragma unroll
    for (int ni = 0; ni < 4; ni++)
      b[ni] = *(const v8s*)&B_lds[buf][(wn * 64 + ni * 16 + l15) * 32 + k8];
    // prefetch tile ks+1 into the other buffer; flies under the MFMAs
    if (ks < 31) G_STAGE(ks + 1, buf ^ 1);
    __builtin_amdgcn_s_setprio(1);
#pragma unroll
    for (int mi = 0; mi < 4; mi++)
#pragma unroll
      for (int ni = 0; ni < 4; ni++)
        acc[mi][ni] = __builtin_amdgcn_mfma_f32_16x16x32_bf16(a[mi], b[ni], acc[mi][ni], 0, 0, 0);
    __builtin_amdgcn_s_setprio(0);
    __syncthreads();  // drains prefetch; all waves done reading buf
  }
#undef G_STAGE

  const int grp = lane >> 4;
#pragma unroll
  for (int mi = 0; mi < 4; mi++) {
#pragma unroll
    for (int ni = 0; ni < 4; ni++) {
      if (MODE == 0) {
        int w01 = cvtpk(acc[mi][ni][0], acc[mi][ni][1]);
        int w23 = cvtpk(acc[mi][ni][2], acc[mi][ni][3]);
        u16 h[4] = {(u16)w01, (u16)(w01 >> 16), (u16)w23, (u16)(w23 >> 16)};
#pragma unroll
        for (int r = 0; r < 4; r++) {
          int row = m0 + wm * 64 + mi * 16 + grp * 4 + r;
          int col = n0 + wn * 64 + ni * 16 + l15;
          int bb = row >> 11, ss = row & 2047;
          int hh = col >> 6, dd = col & 63;
          ((u16*)Cout)[((((size_t)bb * HEADS + hh) * SEQ + ss) << 6) + dd] = h[r];
        }
      } else {
#pragma unroll
        for (int r = 0; r < 4; r++) {
          int row = m0 + wm * 64 + mi * 16 + grp * 4 + r;
          int col = n0 + wn * 64 + ni * 16 + l15;
          ((float*)Cout)[(size_t)row * HD + col] = acc[mi][ni][r];
        }
      }
    }
  }
}

// ---- flash attention: swapped QK^T, XOR-swizzled reg-staged dbuf K/V,
//      issue-early/write-late staging, 1 barrier/tile, ones-MFMA l-sum ----
__global__ __launch_bounds__(256) void attn_kernel(const u16* __restrict__ Q,
                                                   const u16* __restrict__ Kmat,
                                                   const u16* __restrict__ Vt,
                                                   u16* __restrict__ AO) {
  __shared__ u16 K_lds[2][64 * 64];   // [key][d] swizzled, 128B rows
  __shared__ u16 V_lds[2][64 * 64];   // [d][key] swizzled
  __shared__ u16 P_lds[4][16][72];    // per-wave P^T, padded linear

  const int tid = threadIdx.x;
  const int lane = tid & 63;
  const int wv = tid >> 6;
  const int l15 = lane & 15;
  const int grp = lane >> 4;
  const int k8 = grp * 8;

  const int bid = blockIdx.x;
  const int swz = (bid & 7) * 256 + (bid >> 3);  // 8 bh per XCD -> K/V L2-fit
  const int bh = swz >> 5;
  const int qt = swz & 31;
  const size_t base = (size_t)bh * SEQ * DK;

  // Q pre-scaled by (1/sqrt(64)) * log2(e) -> scores in log2 domain
  v8s qf[2];
  {
    const int q = qt * 64 + wv * 16 + l15;
    const u16* qp = Q + base + (size_t)q * DK;
    qf[0] = *(const v8s*)(qp + k8);
    qf[1] = *(const v8s*)(qp + 32 + k8);
    const float SCL = 0.125f * 1.44269504f;
#pragma unroll
    for (int j = 0; j < 8; j++) {
      union { float f; u32 u; } a;
      a.u = ((u32)(u16)qf[0][j]) << 16; a.f *= SCL; qf[0][j] = (short)f2bf(a.f);
      a.u = ((u32)(u16)qf[1][j]) << 16; a.f *= SCL; qf[1][j] = (short)f2bf(a.f);
    }
  }

  v8s ones;
#pragma unroll
  for (int j = 0; j < 8; j++) ones[j] = (short)0x3F80;  // bf16 1.0

  float mrow = -1e30f;
  v4f oacc[5];  // [0..3]: O^T d-blocks; [4]: l row-sum via ones-MFMA
#pragma unroll
  for (int db = 0; db < 5; db++) oacc[db] = (v4f)0.f;

  const int srow = tid >> 2;     // 0..63
  const int a3 = tid & 3;        // 32B chunk within 128B row
  const int sw = srow & 7;
  const u16* kp_base = Kmat + base + (size_t)srow * DK + a3 * 16;
  const u16* vp_base = Vt + base + (size_t)srow * SEQ + a3 * 16;

  int4 kr0, kr1, vr0, vr1;  // staging registers (issue-early / write-late)
#define A_LOAD(t)                                                  \
  do {                                                             \
    const u16* kp = kp_base + (size_t)(t) * 64 * DK;               \
    const u16* vp = vp_base + (t) * 64;                            \
    kr0 = ((const int4*)kp)[0];                                    \
    kr1 = ((const int4*)kp)[1];                                    \
    vr0 = ((const int4*)vp)[0];                                    \
    vr1 = ((const int4*)vp)[1];                                    \
  } while (0)
#define A_WRITE(b)                                                 \
  do {                                                             \
    u16* kr = &K_lds[b][srow << 6];                                \
    u16* vr = &V_lds[b][srow << 6];                                \
    *(int4*)((char*)kr + (((2 * a3 + 0) ^ sw) << 4)) = kr0;        \
    *(int4*)((char*)kr + (((2 * a3 + 1) ^ sw) << 4)) = kr1;        \
    *(int4*)((char*)vr + (((2 * a3 + 0) ^ sw) << 4)) = vr0;        \
    *(int4*)((char*)vr + (((2 * a3 + 1) ^ sw) << 4)) = vr1;        \
  } while (0)

  A_LOAD(0);
  A_WRITE(0);
  __syncthreads();  // buf 0 ready

  for (int t = 0; t < SEQ / 64; ++t) {
    const int buf = t & 1;
    const bool pre = (t + 1 < SEQ / 64);
    if (pre) A_LOAD(t + 1);  // global loads fly under QK^T + softmax

    // S^T[key][q] = K · Q^T
    v4f sacc[4];
#pragma unroll
    for (int kb = 0; kb < 4; kb++) sacc[kb] = (v4f)0.f;
    __builtin_amdgcn_s_setprio(1);
#pragma unroll
    for (int ks = 0; ks < 2; ks++)
#pragma unroll
      for (int kb = 0; kb < 4; kb++) {
        v8s kf = lds_read_swz(K_lds[buf], kb * 16 + l15, ks * 4 + grp);
        sacc[kb] = __builtin_amdgcn_mfma_f32_16x16x32_bf16(kf, qf[ks], sacc[kb], 0, 0, 0);
      }
    __builtin_amdgcn_s_setprio(0);

    // row max: max3 tree then cross-lane over grp
    float m1 = max3f(sacc[0][0], sacc[0][1], sacc[0][2]);
    float m2 = max3f(sacc[0][3], sacc[1][0], sacc[1][1]);
    float m3 = max3f(sacc[1][2], sacc[1][3], sacc[2][0]);
    float m4 = max3f(sacc[2][1], sacc[2][2], sacc[2][3]);
    float m5 = max3f(sacc[3][0], sacc[3][1], sacc[3][2]);
    float mx = fmaxf(max3f(m1, m2, m3), max3f(m4, m5, sacc[3][3]));
    mx = fmaxf(mx, __shfl_xor(mx, 16));
    mx = fmaxf(mx, __shfl_xor(mx, 32));
    // defer-max: rescale only when max grew > 8 (log2 domain; P <= 256)
    if (__any(mx - mrow > 8.f)) {
      float mnew = fmaxf(mrow, mx);
      float fac = __builtin_amdgcn_exp2f(mrow - mnew);
#pragma unroll
      for (int db = 0; db < 5; db++) oacc[db] *= fac;
      mrow = mnew;
    }
    float p[4][4];
#pragma unroll
    for (int kb = 0; kb < 4; kb++)
#pragma unroll
      for (int r = 0; r < 4; r++)
        p[kb][r] = __builtin_amdgcn_exp2f(sacc[kb][r] - mrow);

    // write-late: K/V for t+1 into the other buffer (readers finished at t-1)
    if (pre) A_WRITE(buf ^ 1);

    // P^T -> per-wave LDS (b64 writes, cvt_pk packed)
#pragma unroll
    for (int kb = 0; kb < 4; kb++) {
      int2 w;
      w.x = cvtpk(p[kb][0], p[kb][1]);
      w.y = cvtpk(p[kb][2], p[kb][3]);
      *(int2*)&P_lds[wv][l15][kb * 16 + grp * 4] = w;
    }
    asm volatile("s_waitcnt lgkmcnt(0)" ::: "memory");

    // O^T += V^T · P^T ; 5th block (A=ones) accumulates l in the matrix pipe
    __builtin_amdgcn_s_setprio(1);
#pragma unroll
    for (int ks = 0; ks < 2; ks++) {
      v8s pf = *(const v8s*)&P_lds[wv][l15][ks * 32 + k8];
#pragma unroll
      for (int db = 0; db < 4; db++) {
        v8s vf = lds_read_swz(V_lds[buf], db * 16 + l15, ks * 4 + grp);
        oacc[db] = __builtin_amdgcn_mfma_f32_16x16x32_bf16(vf, pf, oacc[db], 0, 0, 0);
      }
      oacc[4] = __builtin_amdgcn_mfma_f32_16x16x32_bf16(ones, pf, oacc[4], 0, 0, 0);
    }
    __builtin_amdgcn_s_setprio(0);
    __syncthreads();  // single barrier: buf readers done + buf^1 writes visible
  }
#undef A_LOAD
#undef A_WRITE

  const int bb = bh >> 4, hh = bh & 15;
  const int q = qt * 64 + wv * 16 + l15;
  const float inv = 1.0f / oacc[4][0];
  const size_t rowbase = ((size_t)bb * SEQ + q) * HD + hh * DK;
#pragma unroll
  for (int db = 0; db < 4; db++) {
    int2 w;
    w.x = cvtpk(oacc[db][0] * inv, oacc[db][1] * inv);
    w.y = cvtpk(oacc[db][2] * inv, oacc[db][3] * inv);
    *(int2*)&AO[rowbase + db * 16 + grp * 4] = w;
  }
}

extern "C" void kernel_launch(void* const* d_in, const int* in_sizes, int n_in,
                              void* d_out, int out_size, void* d_ws, size_t ws_size,
                              hipStream_t stream) {
  const float* q_in = (const float*)d_in[0];
  const float* k_in = (const float*)d_in[1];
  const float* v_in = (const float*)d_in[2];
  const float* Wq = (const float*)d_in[3];
  const float* Wk = (const float*)d_in[4];
  const float* Wv = (const float*)d_in[5];
  const float* Wo = (const float*)d_in[6];
  float* out = (float*)d_out;

  u16* ws = (u16*)d_ws;
  const size_t M1 = (size_t)1 << 20;
  u16* Wtq = ws;             // 4 x [1024][1024] bf16 (8MB)
  u16* Wtk = Wtq + M1;
  u16* Wtv = Wtk + M1;
  u16* Wto = Wtv + M1;
  u16* X  = Wto + M1;                  // 16MB scratch: bf16 activations / Vt
  u16* Qb = X + (size_t)MROWS * DIN;   // [B*H][S][64] bf16
  u16* Kb = Qb + (size_t)MROWS * HD;
  u16* Vb = Kb + (size_t)MROWS * HD;
  u16* AO = Vb + (size_t)MROWS * HD;   // [B*S][1024] bf16   (total 88MB)
  u16* Vt = X;                         // reuse X after QKV GEMMs

  dim3 tb(256);
  wtrans4_kernel<<<dim3(16, 16, 4), tb, 0, stream>>>(Wq, Wk, Wv, Wo, Wtq, Wtk, Wtv, Wto);

  const int cvtg = MROWS * DIN / 8 / 256;  // 4096
  cvt_kernel<<<dim3(cvtg), tb, 0, stream>>>(q_in, X);
  gemm128_kernel<0><<<dim3(512), tb, 0, stream>>>(X, Wtq, Qb);
  cvt_kernel<<<dim3(cvtg), tb, 0, stream>>>(k_in, X);
  gemm128_kernel<0><<<dim3(512), tb, 0, stream>>>(X, Wtk, Kb);
  cvt_kernel<<<dim3(cvtg), tb, 0, stream>>>(v_in, X);
  gemm128_kernel<0><<<dim3(512), tb, 0, stream>>>(X, Wtv, Vb);

  vtrans_kernel<<<dim3(SEQ / 64, BATCH * HEADS), tb, 0, stream>>>(Vb, Vt);

  attn_kernel<<<dim3(2048), tb, 0, stream>>>(Qb, Kb, Vt, AO);

  gemm128_kernel<1><<<dim3(512), tb, 0, stream>>>(AO, Wto, out);
}

// Round 10
// 252.682 us; speedup vs baseline: 1.7899x; 1.0280x over previous
//
#include <hip/hip_runtime.h>
#include <hip/hip_bf16.h>

// MHA: cvt->proj(QKV via DMA dbuf MFMA GEMM) -> flash attention (single-buffer
// swizzled K/V, issue-early/write-late reg staging) -> out proj.
#define DIN   1024
#define HEADS 16
#define DK    64
#define BATCH 4
#define SEQ   2048
#define MROWS (BATCH*SEQ)   /* 8192 */
#define HD    (HEADS*DK)    /* 1024 */

typedef unsigned short u16;
typedef unsigned int   u32;
typedef __attribute__((ext_vector_type(8))) short v8s;
typedef __attribute__((ext_vector_type(4))) float v4f;

__device__ __forceinline__ u16 f2bf(float x) {
  union { float f; u32 u; } v; v.f = x;
  u32 r = v.u + 0x7FFFu + ((v.u >> 16) & 1u);
  return (u16)(r >> 16);
}
__device__ __forceinline__ int cvtpk(float lo, float hi) {
  int r;
  asm("v_cvt_pk_bf16_f32 %0, %1, %2" : "=v"(r) : "v"(lo), "v"(hi));
  return r;
}
__device__ __forceinline__ float max3f(float a, float b, float c) {
  float r;
  asm("v_max3_f32 %0, %1, %2, %3" : "=v"(r) : "v"(a), "v"(b), "v"(c));
  return r;
}
__device__ __forceinline__ void gload16(const void* g, void* l) {
  __builtin_amdgcn_global_load_lds(
      (__attribute__((address_space(1))) void*)(uintptr_t)(g),
      (__attribute__((address_space(3))) void*)(uintptr_t)(l), 16, 0, 0);
}
// swizzled access into flat [64 rows][8 units of 16B] tile: phys unit = u ^ (row&7)
__device__ __forceinline__ v8s lds_read_swz(const u16* base, int row, int unit) {
  return *(const v8s*)((const char*)base + (row << 7) + (((unit) ^ (row & 7)) << 4));
}

// ---- weight transpose x4: W[k][n] f32 -> Wt[n][k] bf16 ----
__global__ __launch_bounds__(256) void wtrans4_kernel(
    const float* __restrict__ w0, const float* __restrict__ w1,
    const float* __restrict__ w2, const float* __restrict__ w3,
    u16* __restrict__ o0, u16* __restrict__ o1,
    u16* __restrict__ o2, u16* __restrict__ o3) {
  __shared__ float tile[64][65];
  const float* in = blockIdx.z == 0 ? w0 : blockIdx.z == 1 ? w1 : blockIdx.z == 2 ? w2 : w3;
  u16* out = blockIdx.z == 0 ? o0 : blockIdx.z == 1 ? o1 : blockIdx.z == 2 ? o2 : o3;
  int bx = blockIdx.x * 64;
  int by = blockIdx.y * 64;
  for (int i = threadIdx.x; i < 64 * 64; i += 256) {
    int r = i >> 6, c = i & 63;
    tile[r][c] = in[(size_t)(by + r) * DIN + bx + c];
  }
  __syncthreads();
  for (int i = threadIdx.x; i < 64 * 64; i += 256) {
    int r = i >> 6, c = i & 63;
    out[(size_t)(bx + r) * DIN + by + c] = f2bf(tile[c][r]);
  }
}

// ---- f32 -> bf16 convert (8 elems/thread) ----
__global__ __launch_bounds__(256) void cvt_kernel(const float* __restrict__ in,
                                                  u16* __restrict__ out) {
  int i = blockIdx.x * 256 + threadIdx.x;
  const float4* p = (const float4*)(in + (size_t)i * 8);
  float4 a = p[0], b = p[1];
  int4 w;
  w.x = cvtpk(a.x, a.y);
  w.y = cvtpk(a.z, a.w);
  w.z = cvtpk(b.x, b.y);
  w.w = cvtpk(b.z, b.w);
  *(int4*)(out + (size_t)i * 8) = w;
}

// ---- V transpose: Vb[bh][s][d] bf16 -> Vt[bh][d][s] bf16 ----
__global__ __launch_bounds__(256) void vtrans_kernel(const u16* __restrict__ in,
                                                     u16* __restrict__ out) {
  __shared__ u16 t[64][72];
  const int s0 = blockIdx.x * 64;
  const int bh = blockIdx.y;
  const int r = threadIdx.x >> 2;
  const int c = (threadIdx.x & 3) * 16;
  const u16* ip = in + (size_t)bh * SEQ * DK + (size_t)(s0 + r) * DK + c;
  *(int4*)&t[r][c] = ((const int4*)ip)[0];
  *(int4*)&t[r][c + 8] = ((const int4*)ip)[1];
  __syncthreads();
  u16 tmp[16];
#pragma unroll
  for (int j = 0; j < 16; j++) tmp[j] = t[c + j][r];
  u16* op = out + (size_t)bh * DK * SEQ + (size_t)r * SEQ + s0 + c;
  ((int4*)op)[0] = *(int4*)&tmp[0];
  ((int4*)op)[1] = *(int4*)&tmp[8];
}

// ---- 128x128 GEMM, K=1024, bf16, DMA double-buffer, 1 barrier / K-step.
// MODE 0: out bf16 scattered to [B,H,S,dk].  MODE 1: out f32 linear. ----
template <int MODE>
__global__ __launch_bounds__(256) void gemm128_kernel(const u16* __restrict__ A,
                                                      const u16* __restrict__ Bt,
                                                      void* __restrict__ Cout) {
  __shared__ u16 A_lds[2][128 * 32];
  __shared__ u16 B_lds[2][128 * 32];
  const int tid = threadIdx.x;
  const int lane = tid & 63;
  const int wv = tid >> 6;
  const int wm = wv & 1, wn = wv >> 1;
  const int bid = blockIdx.x;
  const int swz = (bid & 7) * 64 + (bid >> 3);  // 512 % 8 == 0, bijective
  const int m0 = (swz >> 3) * 128;
  const int n0 = (swz & 7) * 128;
  const int l15 = lane & 15;
  const int k8 = (lane >> 4) * 8;

  const u16* ga = A + (size_t)(m0 + wv * 16 + (lane >> 2)) * DIN + (lane & 3) * 8;
  const u16* gb = Bt + (size_t)(n0 + wv * 16 + (lane >> 2)) * DIN + (lane & 3) * 8;

  v4f acc[4][4];
#pragma unroll
  for (int i = 0; i < 4; i++)
#pragma unroll
    for (int j = 0; j < 4; j++) acc[i][j] = (v4f)0.f;

#define G_STAGE(ks, b)                                              \
  do {                                                              \
    gload16(ga + (ks) * 32, &A_lds[b][wv * 512]);                   \
    gload16(ga + (size_t)64 * DIN + (ks) * 32, &A_lds[b][wv * 512 + 2048]); \
    gload16(gb + (ks) * 32, &B_lds[b][wv * 512]);                   \
    gload16(gb + (size_t)64 * DIN + (ks) * 32, &B_lds[b][wv * 512 + 2048]); \
  } while (0)

  G_STAGE(0, 0);
  __syncthreads();  // tile 0 landed (vmcnt(0) drain in syncthreads)
  for (int ks = 0; ks < 32; ++ks) {
    const int buf = ks & 1;
    // fragment reads first (so compiler needn't order them vs the new DMA)
    v8s a[4], b[4];
#pragma unroll
    for (int mi = 0; mi < 4; mi++)
      a[mi] = *(const v8s*)&A_lds[buf][(wm * 64 + mi * 16 + l15) * 32 + k8];
#pragma unroll
    for (int ni = 0; ni < 4; ni++)
      b[ni] = *(const v8s*)&B_lds[buf][(wn * 64 + ni * 16 + l15) * 32 + k8];
    // prefetch tile ks+1 into the other buffer; flies under the MFMAs
    if (ks < 31) G_STAGE(ks + 1, buf ^ 1);
    __builtin_amdgcn_s_setprio(1);
#pragma unroll
    for (int mi = 0; mi < 4; mi++)
#pragma unroll
      for (int ni = 0; ni < 4; ni++)
        acc[mi][ni] = __builtin_amdgcn_mfma_f32_16x16x32_bf16(a[mi], b[ni], acc[mi][ni], 0, 0, 0);
    __builtin_amdgcn_s_setprio(0);
    __syncthreads();  // drains prefetch; all waves done reading buf
  }
#undef G_STAGE

  const int grp = lane >> 4;
#pragma unroll
  for (int mi = 0; mi < 4; mi++) {
#pragma unroll
    for (int ni = 0; ni < 4; ni++) {
      if (MODE == 0) {
        int w01 = cvtpk(acc[mi][ni][0], acc[mi][ni][1]);
        int w23 = cvtpk(acc[mi][ni][2], acc[mi][ni][3]);
        u16 h[4] = {(u16)w01, (u16)(w01 >> 16), (u16)w23, (u16)(w23 >> 16)};
#pragma unroll
        for (int r = 0; r < 4; r++) {
          int row = m0 + wm * 64 + mi * 16 + grp * 4 + r;
          int col = n0 + wn * 64 + ni * 16 + l15;
          int bb = row >> 11, ss = row & 2047;
          int hh = col >> 6, dd = col & 63;
          ((u16*)Cout)[((((size_t)bb * HEADS + hh) * SEQ + ss) << 6) + dd] = h[r];
        }
      } else {
#pragma unroll
        for (int r = 0; r < 4; r++) {
          int row = m0 + wm * 64 + mi * 16 + grp * 4 + r;
          int col = n0 + wn * 64 + ni * 16 + l15;
          ((float*)Cout)[(size_t)row * HD + col] = acc[mi][ni][r];
        }
      }
    }
  }
}

// ---- flash attention: swapped QK^T, XOR-swizzled single-buffer K/V,
//      issue-early/write-late reg staging (T14), ones-MFMA l-sum ----
__global__ __launch_bounds__(256) void attn_kernel(const u16* __restrict__ Q,
                                                   const u16* __restrict__ Kmat,
                                                   const u16* __restrict__ Vt,
                                                   u16* __restrict__ AO) {
  __shared__ u16 K_lds[64 * 64];   // [key][d] swizzled, 128B rows
  __shared__ u16 V_lds[64 * 64];   // [d][key] swizzled
  __shared__ u16 P_lds[4][16][72]; // per-wave P^T, padded linear

  const int tid = threadIdx.x;
  const int lane = tid & 63;
  const int wv = tid >> 6;
  const int l15 = lane & 15;
  const int grp = lane >> 4;
  const int k8 = grp * 8;

  const int bid = blockIdx.x;
  const int swz = (bid & 7) * 256 + (bid >> 3);  // 8 bh per XCD -> K/V L2-fit
  const int bh = swz >> 5;
  const int qt = swz & 31;
  const size_t base = (size_t)bh * SEQ * DK;

  // Q pre-scaled by (1/sqrt(64)) * log2(e) -> scores in log2 domain
  v8s qf[2];
  {
    const int q = qt * 64 + wv * 16 + l15;
    const u16* qp = Q + base + (size_t)q * DK;
    qf[0] = *(const v8s*)(qp + k8);
    qf[1] = *(const v8s*)(qp + 32 + k8);
    const float SCL = 0.125f * 1.44269504f;
#pragma unroll
    for (int j = 0; j < 8; j++) {
      union { float f; u32 u; } a;
      a.u = ((u32)(u16)qf[0][j]) << 16; a.f *= SCL; qf[0][j] = (short)f2bf(a.f);
      a.u = ((u32)(u16)qf[1][j]) << 16; a.f *= SCL; qf[1][j] = (short)f2bf(a.f);
    }
  }

  v8s ones;
#pragma unroll
  for (int j = 0; j < 8; j++) ones[j] = (short)0x3F80;  // bf16 1.0

  float mrow = -1e30f;
  v4f oacc[5];  // [0..3]: O^T d-blocks; [4]: l row-sum via ones-MFMA
#pragma unroll
  for (int db = 0; db < 5; db++) oacc[db] = (v4f)0.f;

  const int srow = tid >> 2;     // 0..63
  const int a3 = tid & 3;        // 32B chunk within 128B row
  const int sw = srow & 7;
  const u16* kp_base = Kmat + base + (size_t)srow * DK + a3 * 16;
  const u16* vp_base = Vt + base + (size_t)srow * SEQ + a3 * 16;
  u16* krow = &K_lds[srow << 6];
  u16* vrow = &V_lds[srow << 6];

  int4 kr0, kr1, vr0, vr1;  // staging registers (issue-early / write-late)
#define A_LOAD(t)                                                  \
  do {                                                             \
    const u16* kp = kp_base + (size_t)(t) * 64 * DK;               \
    const u16* vp = vp_base + (t) * 64;                            \
    kr0 = ((const int4*)kp)[0];                                    \
    kr1 = ((const int4*)kp)[1];                                    \
    vr0 = ((const int4*)vp)[0];                                    \
    vr1 = ((const int4*)vp)[1];                                    \
  } while (0)
#define A_WRITE()                                                  \
  do {                                                             \
    *(int4*)((char*)krow + (((2 * a3 + 0) ^ sw) << 4)) = kr0;      \
    *(int4*)((char*)krow + (((2 * a3 + 1) ^ sw) << 4)) = kr1;      \
    *(int4*)((char*)vrow + (((2 * a3 + 0) ^ sw) << 4)) = vr0;      \
    *(int4*)((char*)vrow + (((2 * a3 + 1) ^ sw) << 4)) = vr1;      \
  } while (0)

  A_LOAD(0);

  for (int t = 0; t < SEQ / 64; ++t) {
    __syncthreads();   // barrier_a: all waves done reading tile t-1
    A_WRITE();         // store tile t (compiler waits its own vmcnt for regs)
    __syncthreads();   // barrier_b: tile t visible to all waves
    if (t + 1 < SEQ / 64) A_LOAD(t + 1);  // loads fly under compute(t)

    // S^T[key][q] = K · Q^T
    v4f sacc[4];
#pragma unroll
    for (int kb = 0; kb < 4; kb++) sacc[kb] = (v4f)0.f;
    __builtin_amdgcn_s_setprio(1);
#pragma unroll
    for (int ks = 0; ks < 2; ks++)
#pragma unroll
      for (int kb = 0; kb < 4; kb++) {
        v8s kf = lds_read_swz(K_lds, kb * 16 + l15, ks * 4 + grp);
        sacc[kb] = __builtin_amdgcn_mfma_f32_16x16x32_bf16(kf, qf[ks], sacc[kb], 0, 0, 0);
      }
    __builtin_amdgcn_s_setprio(0);

    // row max: max3 tree then cross-lane over grp
    float m1 = max3f(sacc[0][0], sacc[0][1], sacc[0][2]);
    float m2 = max3f(sacc[0][3], sacc[1][0], sacc[1][1]);
    float m3 = max3f(sacc[1][2], sacc[1][3], sacc[2][0]);
    float m4 = max3f(sacc[2][1], sacc[2][2], sacc[2][3]);
    float m5 = max3f(sacc[3][0], sacc[3][1], sacc[3][2]);
    float mx = fmaxf(max3f(m1, m2, m3), max3f(m4, m5, sacc[3][3]));
    mx = fmaxf(mx, __shfl_xor(mx, 16));
    mx = fmaxf(mx, __shfl_xor(mx, 32));
    // defer-max: rescale only when max grew > 8 (log2 domain; P <= 256)
    if (__any(mx - mrow > 8.f)) {
      float mnew = fmaxf(mrow, mx);
      float fac = __builtin_amdgcn_exp2f(mrow - mnew);
#pragma unroll
      for (int db = 0; db < 5; db++) oacc[db] *= fac;
      mrow = mnew;
    }
    float p[4][4];
#pragma unroll
    for (int kb = 0; kb < 4; kb++)
#pragma unroll
      for (int r = 0; r < 4; r++)
        p[kb][r] = __builtin_amdgcn_exp2f(sacc[kb][r] - mrow);

    // P^T -> per-wave LDS (b64 writes, cvt_pk packed)
#pragma unroll
    for (int kb = 0; kb < 4; kb++) {
      int2 w;
      w.x = cvtpk(p[kb][0], p[kb][1]);
      w.y = cvtpk(p[kb][2], p[kb][3]);
      *(int2*)&P_lds[wv][l15][kb * 16 + grp * 4] = w;
    }
    asm volatile("s_waitcnt lgkmcnt(0)" ::: "memory");

    // O^T += V^T · P^T ; 5th block (A=ones) accumulates l in the matrix pipe
    __builtin_amdgcn_s_setprio(1);
#pragma unroll
    for (int ks = 0; ks < 2; ks++) {
      v8s pf = *(const v8s*)&P_lds[wv][l15][ks * 32 + k8];
#pragma unroll
      for (int db = 0; db < 4; db++) {
        v8s vf = lds_read_swz(V_lds, db * 16 + l15, ks * 4 + grp);
        oacc[db] = __builtin_amdgcn_mfma_f32_16x16x32_bf16(vf, pf, oacc[db], 0, 0, 0);
      }
      oacc[4] = __builtin_amdgcn_mfma_f32_16x16x32_bf16(ones, pf, oacc[4], 0, 0, 0);
    }
    __builtin_amdgcn_s_setprio(0);
  }
#undef A_LOAD
#undef A_WRITE

  const int bb = bh >> 4, hh = bh & 15;
  const int q = qt * 64 + wv * 16 + l15;
  const float inv = 1.0f / oacc[4][0];
  const size_t rowbase = ((size_t)bb * SEQ + q) * HD + hh * DK;
#pragma unroll
  for (int db = 0; db < 4; db++) {
    int2 w;
    w.x = cvtpk(oacc[db][0] * inv, oacc[db][1] * inv);
    w.y = cvtpk(oacc[db][2] * inv, oacc[db][3] * inv);
    *(int2*)&AO[rowbase + db * 16 + grp * 4] = w;
  }
}

extern "C" void kernel_launch(void* const* d_in, const int* in_sizes, int n_in,
                              void* d_out, int out_size, void* d_ws, size_t ws_size,
                              hipStream_t stream) {
  const float* q_in = (const float*)d_in[0];
  const float* k_in = (const float*)d_in[1];
  const float* v_in = (const float*)d_in[2];
  const float* Wq = (const float*)d_in[3];
  const float* Wk = (const float*)d_in[4];
  const float* Wv = (const float*)d_in[5];
  const float* Wo = (const float*)d_in[6];
  float* out = (float*)d_out;

  u16* ws = (u16*)d_ws;
  const size_t M1 = (size_t)1 << 20;
  u16* Wtq = ws;             // 4 x [1024][1024] bf16 (8MB)
  u16* Wtk = Wtq + M1;
  u16* Wtv = Wtk + M1;
  u16* Wto = Wtv + M1;
  u16* X  = Wto + M1;                  // 16MB scratch: bf16 activations / Vt
  u16* Qb = X + (size_t)MROWS * DIN;   // [B*H][S][64] bf16
  u16* Kb = Qb + (size_t)MROWS * HD;
  u16* Vb = Kb + (size_t)MROWS * HD;
  u16* AO = Vb + (size_t)MROWS * HD;   // [B*S][1024] bf16   (total 88MB)
  u16* Vt = X;                         // reuse X after QKV GEMMs

  dim3 tb(256);
  wtrans4_kernel<<<dim3(16, 16, 4), tb, 0, stream>>>(Wq, Wk, Wv, Wo, Wtq, Wtk, Wtv, Wto);

  const int cvtg = MROWS * DIN / 8 / 256;  // 4096
  cvt_kernel<<<dim3(cvtg), tb, 0, stream>>>(q_in, X);
  gemm128_kernel<0><<<dim3(512), tb, 0, stream>>>(X, Wtq, Qb);
  cvt_kernel<<<dim3(cvtg), tb, 0, stream>>>(k_in, X);
  gemm128_kernel<0><<<dim3(512), tb, 0, stream>>>(X, Wtk, Kb);
  cvt_kernel<<<dim3(cvtg), tb, 0, stream>>>(v_in, X);
  gemm128_kernel<0><<<dim3(512), tb, 0, stream>>>(X, Wtv, Vb);

  vtrans_kernel<<<dim3(SEQ / 64, BATCH * HEADS), tb, 0, stream>>>(Vb, Vt);

  attn_kernel<<<dim3(2048), tb, 0, stream>>>(Qb, Kb, Vt, AO);

  gemm128_kernel<1><<<dim3(512), tb, 0, stream>>>(AO, Wto, out);
}

// Round 13
// 230.400 us; speedup vs baseline: 1.9630x; 1.0967x over previous
//
#include <hip/hip_runtime.h>
#include <hip/hip_bf16.h>

// MHA: cvt->proj(QKV via DMA dbuf MFMA GEMM) -> flash attention (8 waves/block,
// 128 q-rows share staged K/V; per-wave pipeline identical to R10) -> out proj.
#define DIN   1024
#define HEADS 16
#define DK    64
#define BATCH 4
#define SEQ   2048
#define MROWS (BATCH*SEQ)   /* 8192 */
#define HD    (HEADS*DK)    /* 1024 */

typedef unsigned short u16;
typedef unsigned int   u32;
typedef __attribute__((ext_vector_type(8))) short v8s;
typedef __attribute__((ext_vector_type(4))) float v4f;

__device__ __forceinline__ u16 f2bf(float x) {
  union { float f; u32 u; } v; v.f = x;
  u32 r = v.u + 0x7FFFu + ((v.u >> 16) & 1u);
  return (u16)(r >> 16);
}
__device__ __forceinline__ int cvtpk(float lo, float hi) {
  int r;
  asm("v_cvt_pk_bf16_f32 %0, %1, %2" : "=v"(r) : "v"(lo), "v"(hi));
  return r;
}
__device__ __forceinline__ float max3f(float a, float b, float c) {
  float r;
  asm("v_max3_f32 %0, %1, %2, %3" : "=v"(r) : "v"(a), "v"(b), "v"(c));
  return r;
}
__device__ __forceinline__ void gload16(const void* g, void* l) {
  __builtin_amdgcn_global_load_lds(
      (__attribute__((address_space(1))) void*)(uintptr_t)(g),
      (__attribute__((address_space(3))) void*)(uintptr_t)(l), 16, 0, 0);
}
// swizzled access into flat [64 rows][8 units of 16B] tile: phys unit = u ^ (row&7)
__device__ __forceinline__ v8s lds_read_swz(const u16* base, int row, int unit) {
  return *(const v8s*)((const char*)base + (row << 7) + (((unit) ^ (row & 7)) << 4));
}

// ---- weight transpose x4: W[k][n] f32 -> Wt[n][k] bf16 ----
__global__ __launch_bounds__(256) void wtrans4_kernel(
    const float* __restrict__ w0, const float* __restrict__ w1,
    const float* __restrict__ w2, const float* __restrict__ w3,
    u16* __restrict__ o0, u16* __restrict__ o1,
    u16* __restrict__ o2, u16* __restrict__ o3) {
  __shared__ float tile[64][65];
  const float* in = blockIdx.z == 0 ? w0 : blockIdx.z == 1 ? w1 : blockIdx.z == 2 ? w2 : w3;
  u16* out = blockIdx.z == 0 ? o0 : blockIdx.z == 1 ? o1 : blockIdx.z == 2 ? o2 : o3;
  int bx = blockIdx.x * 64;
  int by = blockIdx.y * 64;
  for (int i = threadIdx.x; i < 64 * 64; i += 256) {
    int r = i >> 6, c = i & 63;
    tile[r][c] = in[(size_t)(by + r) * DIN + bx + c];
  }
  __syncthreads();
  for (int i = threadIdx.x; i < 64 * 64; i += 256) {
    int r = i >> 6, c = i & 63;
    out[(size_t)(bx + r) * DIN + by + c] = f2bf(tile[c][r]);
  }
}

// ---- f32 -> bf16 convert (8 elems/thread) ----
__global__ __launch_bounds__(256) void cvt_kernel(const float* __restrict__ in,
                                                  u16* __restrict__ out) {
  int i = blockIdx.x * 256 + threadIdx.x;
  const float4* p = (const float4*)(in + (size_t)i * 8);
  float4 a = p[0], b = p[1];
  int4 w;
  w.x = cvtpk(a.x, a.y);
  w.y = cvtpk(a.z, a.w);
  w.z = cvtpk(b.x, b.y);
  w.w = cvtpk(b.z, b.w);
  *(int4*)(out + (size_t)i * 8) = w;
}

// ---- V transpose: Vb[bh][s][d] bf16 -> Vt[bh][d][s] bf16 ----
__global__ __launch_bounds__(256) void vtrans_kernel(const u16* __restrict__ in,
                                                     u16* __restrict__ out) {
  __shared__ u16 t[64][72];
  const int s0 = blockIdx.x * 64;
  const int bh = blockIdx.y;
  const int r = threadIdx.x >> 2;
  const int c = (threadIdx.x & 3) * 16;
  const u16* ip = in + (size_t)bh * SEQ * DK + (size_t)(s0 + r) * DK + c;
  *(int4*)&t[r][c] = ((const int4*)ip)[0];
  *(int4*)&t[r][c + 8] = ((const int4*)ip)[1];
  __syncthreads();
  u16 tmp[16];
#pragma unroll
  for (int j = 0; j < 16; j++) tmp[j] = t[c + j][r];
  u16* op = out + (size_t)bh * DK * SEQ + (size_t)r * SEQ + s0 + c;
  ((int4*)op)[0] = *(int4*)&tmp[0];
  ((int4*)op)[1] = *(int4*)&tmp[8];
}

// ---- 128x128 GEMM, K=1024, bf16, DMA double-buffer, 1 barrier / K-step.
// MODE 0: out bf16 scattered to [B,H,S,dk].  MODE 1: out f32 linear. ----
template <int MODE>
__global__ __launch_bounds__(256) void gemm128_kernel(const u16* __restrict__ A,
                                                      const u16* __restrict__ Bt,
                                                      void* __restrict__ Cout) {
  __shared__ u16 A_lds[2][128 * 32];
  __shared__ u16 B_lds[2][128 * 32];
  const int tid = threadIdx.x;
  const int lane = tid & 63;
  const int wv = tid >> 6;
  const int wm = wv & 1, wn = wv >> 1;
  const int bid = blockIdx.x;
  const int swz = (bid & 7) * 64 + (bid >> 3);  // 512 % 8 == 0, bijective
  const int m0 = (swz >> 3) * 128;
  const int n0 = (swz & 7) * 128;
  const int l15 = lane & 15;
  const int k8 = (lane >> 4) * 8;

  const u16* ga = A + (size_t)(m0 + wv * 16 + (lane >> 2)) * DIN + (lane & 3) * 8;
  const u16* gb = Bt + (size_t)(n0 + wv * 16 + (lane >> 2)) * DIN + (lane & 3) * 8;

  v4f acc[4][4];
#pragma unroll
  for (int i = 0; i < 4; i++)
#pragma unroll
    for (int j = 0; j < 4; j++) acc[i][j] = (v4f)0.f;

#define G_STAGE(ks, b)                                              \
  do {                                                              \
    gload16(ga + (ks) * 32, &A_lds[b][wv * 512]);                   \
    gload16(ga + (size_t)64 * DIN + (ks) * 32, &A_lds[b][wv * 512 + 2048]); \
    gload16(gb + (ks) * 32, &B_lds[b][wv * 512]);                   \
    gload16(gb + (size_t)64 * DIN + (ks) * 32, &B_lds[b][wv * 512 + 2048]); \
  } while (0)

  G_STAGE(0, 0);
  __syncthreads();  // tile 0 landed (vmcnt(0) drain in syncthreads)
  for (int ks = 0; ks < 32; ++ks) {
    const int buf = ks & 1;
    v8s a[4], b[4];
#pragma unroll
    for (int mi = 0; mi < 4; mi++)
      a[mi] = *(const v8s*)&A_lds[buf][(wm * 64 + mi * 16 + l15) * 32 + k8];
#pragma unroll
    for (int ni = 0; ni < 4; ni++)
      b[ni] = *(const v8s*)&B_lds[buf][(wn * 64 + ni * 16 + l15) * 32 + k8];
    if (ks < 31) G_STAGE(ks + 1, buf ^ 1);
    __builtin_amdgcn_s_setprio(1);
#pragma unroll
    for (int mi = 0; mi < 4; mi++)
#pragma unroll
      for (int ni = 0; ni < 4; ni++)
        acc[mi][ni] = __builtin_amdgcn_mfma_f32_16x16x32_bf16(a[mi], b[ni], acc[mi][ni], 0, 0, 0);
    __builtin_amdgcn_s_setprio(0);
    __syncthreads();
  }
#undef G_STAGE

  const int grp = lane >> 4;
#pragma unroll
  for (int mi = 0; mi < 4; mi++) {
#pragma unroll
    for (int ni = 0; ni < 4; ni++) {
      if (MODE == 0) {
        int w01 = cvtpk(acc[mi][ni][0], acc[mi][ni][1]);
        int w23 = cvtpk(acc[mi][ni][2], acc[mi][ni][3]);
        u16 h[4] = {(u16)w01, (u16)(w01 >> 16), (u16)w23, (u16)(w23 >> 16)};
#pragma unroll
        for (int r = 0; r < 4; r++) {
          int row = m0 + wm * 64 + mi * 16 + grp * 4 + r;
          int col = n0 + wn * 64 + ni * 16 + l15;
          int bb = row >> 11, ss = row & 2047;
          int hh = col >> 6, dd = col & 63;
          ((u16*)Cout)[((((size_t)bb * HEADS + hh) * SEQ + ss) << 6) + dd] = h[r];
        }
      } else {
#pragma unroll
        for (int r = 0; r < 4; r++) {
          int row = m0 + wm * 64 + mi * 16 + grp * 4 + r;
          int col = n0 + wn * 64 + ni * 16 + l15;
          ((float*)Cout)[(size_t)row * HD + col] = acc[mi][ni][r];
        }
      }
    }
  }
}

// ---- flash attention: 8 waves/block, 128 q rows share staged K/V; per-wave
// pipeline = R10's (swapped QK^T, XOR-swizzled K/V, T14, ones-MFMA l-sum) ----
__global__ __launch_bounds__(512) void attn_kernel(const u16* __restrict__ Q,
                                                   const u16* __restrict__ Kmat,
                                                   const u16* __restrict__ Vt,
                                                   u16* __restrict__ AO) {
  __shared__ u16 K_lds[64 * 64];   // [key][d] swizzled, 128B rows
  __shared__ u16 V_lds[64 * 64];   // [d][key] swizzled
  __shared__ u16 P_lds[8][16][72]; // per-wave P^T, padded linear

  const int tid = threadIdx.x;
  const int lane = tid & 63;
  const int wv = tid >> 6;         // 0..7
  const int l15 = lane & 15;
  const int grp = lane >> 4;
  const int k8 = grp * 8;

  const int bid = blockIdx.x;                    // 1024 blocks
  const int swz = (bid & 7) * 128 + (bid >> 3);  // 8 bh per XCD -> K/V L2-fit
  const int bh = swz >> 4;                       // 0..63
  const int qt = swz & 15;                       // 0..15
  const size_t base = (size_t)bh * SEQ * DK;

  // Q pre-scaled by (1/sqrt(64)) * log2(e) -> scores in log2 domain
  v8s qf[2];
  {
    const int q = qt * 128 + wv * 16 + l15;
    const u16* qp = Q + base + (size_t)q * DK;
    qf[0] = *(const v8s*)(qp + k8);
    qf[1] = *(const v8s*)(qp + 32 + k8);
    const float SCL = 0.125f * 1.44269504f;
#pragma unroll
    for (int j = 0; j < 8; j++) {
      union { float f; u32 u; } a;
      a.u = ((u32)(u16)qf[0][j]) << 16; a.f *= SCL; qf[0][j] = (short)f2bf(a.f);
      a.u = ((u32)(u16)qf[1][j]) << 16; a.f *= SCL; qf[1][j] = (short)f2bf(a.f);
    }
  }

  v8s ones;
#pragma unroll
  for (int j = 0; j < 8; j++) ones[j] = (short)0x3F80;  // bf16 1.0

  float mrow = -1e30f;
  v4f oacc[5];  // [0..3]: O^T d-blocks; [4]: l row-sum via ones-MFMA
#pragma unroll
  for (int db = 0; db < 5; db++) oacc[db] = (v4f)0.f;

  // staging: 512 threads, one 16B unit each per K and V
  const int srow = tid >> 3;     // 0..63
  const int au = tid & 7;        // unit within 128B row
  const int sw = srow & 7;
  const u16* kp_base = Kmat + base + (size_t)srow * DK + au * 8;
  const u16* vp_base = Vt + base + (size_t)srow * SEQ + au * 8;
  u16* krow = &K_lds[srow << 6];
  u16* vrow = &V_lds[srow << 6];

  int4 kr0, vr0;  // staging registers (issue-early / write-late)
#define A_LOAD(t)                                                  \
  do {                                                             \
    kr0 = *(const int4*)(kp_base + (size_t)(t) * 64 * DK);         \
    vr0 = *(const int4*)(vp_base + (t) * 64);                      \
  } while (0)
#define A_WRITE()                                                  \
  do {                                                             \
    *(int4*)((char*)krow + ((au ^ sw) << 4)) = kr0;                \
    *(int4*)((char*)vrow + ((au ^ sw) << 4)) = vr0;                \
  } while (0)

  A_LOAD(0);

  for (int t = 0; t < SEQ / 64; ++t) {
    __syncthreads();   // all waves done reading tile t-1
    A_WRITE();
    __syncthreads();   // tile t visible
    if (t + 1 < SEQ / 64) A_LOAD(t + 1);  // loads fly under compute(t)

    // S^T[key][q] = K · Q^T
    v4f sacc[4];
#pragma unroll
    for (int kb = 0; kb < 4; kb++) sacc[kb] = (v4f)0.f;
    __builtin_amdgcn_s_setprio(1);
#pragma unroll
    for (int ks = 0; ks < 2; ks++)
#pragma unroll
      for (int kb = 0; kb < 4; kb++) {
        v8s kf = lds_read_swz(K_lds, kb * 16 + l15, ks * 4 + grp);
        sacc[kb] = __builtin_amdgcn_mfma_f32_16x16x32_bf16(kf, qf[ks], sacc[kb], 0, 0, 0);
      }
    __builtin_amdgcn_s_setprio(0);

    // row max: max3 tree then cross-lane over grp
    float m1 = max3f(sacc[0][0], sacc[0][1], sacc[0][2]);
    float m2 = max3f(sacc[0][3], sacc[1][0], sacc[1][1]);
    float m3 = max3f(sacc[1][2], sacc[1][3], sacc[2][0]);
    float m4 = max3f(sacc[2][1], sacc[2][2], sacc[2][3]);
    float m5 = max3f(sacc[3][0], sacc[3][1], sacc[3][2]);
    float mx = fmaxf(max3f(m1, m2, m3), max3f(m4, m5, sacc[3][3]));
    mx = fmaxf(mx, __shfl_xor(mx, 16));
    mx = fmaxf(mx, __shfl_xor(mx, 32));
    // defer-max: rescale only when max grew > 8 (log2 domain; P <= 256)
    if (__any(mx - mrow > 8.f)) {
      float mnew = fmaxf(mrow, mx);
      float fac = __builtin_amdgcn_exp2f(mrow - mnew);
#pragma unroll
      for (int db = 0; db < 5; db++) oacc[db] *= fac;
      mrow = mnew;
    }
    float p[4][4];
#pragma unroll
    for (int kb = 0; kb < 4; kb++)
#pragma unroll
      for (int r = 0; r < 4; r++)
        p[kb][r] = __builtin_amdgcn_exp2f(sacc[kb][r] - mrow);

    // P^T -> per-wave LDS (b64 writes, cvt_pk packed)
#pragma unroll
    for (int kb = 0; kb < 4; kb++) {
      int2 w;
      w.x = cvtpk(p[kb][0], p[kb][1]);
      w.y = cvtpk(p[kb][2], p[kb][3]);
      *(int2*)&P_lds[wv][l15][kb * 16 + grp * 4] = w;
    }
    asm volatile("s_waitcnt lgkmcnt(0)" ::: "memory");

    // O^T += V^T · P^T ; 5th block (A=ones) accumulates l in the matrix pipe
    __builtin_amdgcn_s_setprio(1);
#pragma unroll
    for (int ks = 0; ks < 2; ks++) {
      v8s pf = *(const v8s*)&P_lds[wv][l15][ks * 32 + k8];
#pragma unroll
      for (int db = 0; db < 4; db++) {
        v8s vf = lds_read_swz(V_lds, db * 16 + l15, ks * 4 + grp);
        oacc[db] = __builtin_amdgcn_mfma_f32_16x16x32_bf16(vf, pf, oacc[db], 0, 0, 0);
      }
      oacc[4] = __builtin_amdgcn_mfma_f32_16x16x32_bf16(ones, pf, oacc[4], 0, 0, 0);
    }
    __builtin_amdgcn_s_setprio(0);
  }
#undef A_LOAD
#undef A_WRITE

  const int bb = bh >> 4, hh = bh & 15;
  const int q = qt * 128 + wv * 16 + l15;
  const float inv = 1.0f / oacc[4][0];
  const size_t rowbase = ((size_t)bb * SEQ + q) * HD + hh * DK;
#pragma unroll
  for (int db = 0; db < 4; db++) {
    int2 w;
    w.x = cvtpk(oacc[db][0] * inv, oacc[db][1] * inv);
    w.y = cvtpk(oacc[db][2] * inv, oacc[db][3] * inv);
    *(int2*)&AO[rowbase + db * 16 + grp * 4] = w;
  }
}

extern "C" void kernel_launch(void* const* d_in, const int* in_sizes, int n_in,
                              void* d_out, int out_size, void* d_ws, size_t ws_size,
                              hipStream_t stream) {
  const float* q_in = (const float*)d_in[0];
  const float* k_in = (const float*)d_in[1];
  const float* v_in = (const float*)d_in[2];
  const float* Wq = (const float*)d_in[3];
  const float* Wk = (const float*)d_in[4];
  const float* Wv = (const float*)d_in[5];
  const float* Wo = (const float*)d_in[6];
  float* out = (float*)d_out;

  u16* ws = (u16*)d_ws;
  const size_t M1 = (size_t)1 << 20;
  u16* Wtq = ws;             // 4 x [1024][1024] bf16 (8MB)
  u16* Wtk = Wtq + M1;
  u16* Wtv = Wtk + M1;
  u16* Wto = Wtv + M1;
  u16* X  = Wto + M1;                  // 16MB scratch: bf16 activations / Vt
  u16* Qb = X + (size_t)MROWS * DIN;   // [B*H][S][64] bf16
  u16* Kb = Qb + (size_t)MROWS * HD;
  u16* Vb = Kb + (size_t)MROWS * HD;
  u16* AO = Vb + (size_t)MROWS * HD;   // [B*S][1024] bf16   (total 88MB)
  u16* Vt = X;                         // reuse X after QKV GEMMs

  dim3 tb(256);
  wtrans4_kernel<<<dim3(16, 16, 4), tb, 0, stream>>>(Wq, Wk, Wv, Wo, Wtq, Wtk, Wtv, Wto);

  const int cvtg = MROWS * DIN / 8 / 256;  // 4096
  cvt_kernel<<<dim3(cvtg), tb, 0, stream>>>(q_in, X);
  gemm128_kernel<0><<<dim3(512), tb, 0, stream>>>(X, Wtq, Qb);
  cvt_kernel<<<dim3(cvtg), tb, 0, stream>>>(k_in, X);
  gemm128_kernel<0><<<dim3(512), tb, 0, stream>>>(X, Wtk, Kb);
  cvt_kernel<<<dim3(cvtg), tb, 0, stream>>>(v_in, X);
  gemm128_kernel<0><<<dim3(512), tb, 0, stream>>>(X, Wtv, Vb);

  vtrans_kernel<<<dim3(SEQ / 64, BATCH * HEADS), tb, 0, stream>>>(Vb, Vt);

  attn_kernel<<<dim3(1024), dim3(512), 0, stream>>>(Qb, Kb, Vt, AO);

  gemm128_kernel<1><<<dim3(512), tb, 0, stream>>>(AO, Wto, out);
}